// Round 1
// baseline (411.808 us; speedup 1.0000x reference)
//
#include <hip/hip_runtime.h>
#include <hip/hip_bf16.h>
#include <math.h>

#define DIMD 384
#define NHEADS 6
#define HD 64
#define MLPH 768
#define SEQ 2048
#define NBATCH 4
#define NTOK (NBATCH*SEQ)   // 8192

typedef __hip_bfloat16 bf16;

typedef __attribute__((ext_vector_type(8))) short bf16x8;
typedef __attribute__((ext_vector_type(4))) float f32x4;

static __device__ inline f32x4 mfma16(bf16x8 a, bf16x8 b, f32x4 c) {
    return __builtin_amdgcn_mfma_f32_16x16x32_bf16(a, b, c, 0, 0, 0);
}

static __device__ inline unsigned short bfbits(float f) {
    return __builtin_bit_cast(unsigned short, __float2bfloat16(f));
}
static __device__ inline unsigned int pack2(float lo, float hi) {
    return (unsigned int)bfbits(lo) | ((unsigned int)bfbits(hi) << 16);
}

// ---------------------------------------------------------------- LayerNorm
__global__ __launch_bounds__(256) void ln_k(const float* __restrict__ x,
                                            const float* __restrict__ gm,
                                            const float* __restrict__ bt,
                                            bf16* __restrict__ out) {
    int row = blockIdx.x * 4 + (threadIdx.x >> 6);
    int l = threadIdx.x & 63;
    const float* xr = x + (size_t)row * DIMD;
    float v[6];
#pragma unroll
    for (int j = 0; j < 6; ++j) v[j] = xr[l + 64 * j];
    float s = 0.f, s2 = 0.f;
#pragma unroll
    for (int j = 0; j < 6; ++j) { s += v[j]; s2 += v[j] * v[j]; }
#pragma unroll
    for (int m = 1; m < 64; m <<= 1) { s += __shfl_xor(s, m); s2 += __shfl_xor(s2, m); }
    float mu = s * (1.f / DIMD);
    float var = s2 * (1.f / DIMD) - mu * mu;
    float rs = rsqrtf(var + 1e-5f);
    bf16* orow = out + (size_t)row * DIMD;
#pragma unroll
    for (int j = 0; j < 6; ++j) {
        int i = l + 64 * j;
        orow[i] = __float2bfloat16((v[j] - mu) * rs * gm[i] + bt[i]);
    }
}

// ------------------------------------------------- weight transpose + cast
// W [K][N] f32  ->  WT [N][K] bf16
__global__ __launch_bounds__(256) void wtrans_k(const float* __restrict__ W,
                                                bf16* __restrict__ WT,
                                                int K, int N) {
    __shared__ float t[32][33];
    int tx = threadIdx.x & 31, ty = threadIdx.x >> 5;   // 32 x 8
    int nb = blockIdx.x * 32, kb = blockIdx.y * 32;
#pragma unroll
    for (int i = 0; i < 4; ++i)
        t[ty + 8 * i][tx] = W[(size_t)(kb + ty + 8 * i) * N + nb + tx];
    __syncthreads();
#pragma unroll
    for (int i = 0; i < 4; ++i)
        WT[(size_t)(nb + ty + 8 * i) * K + kb + tx] = __float2bfloat16(t[tx][ty + 8 * i]);
}

// ------------------------------------------------- V transpose (per head)
// v [BH][SEQ][HD] -> vT [BH][HD][SEQ]   (bf16, as raw ushort)
__global__ __launch_bounds__(256) void vtrans_k(const bf16* __restrict__ v_,
                                                bf16* __restrict__ vT_) {
    const unsigned short* v = (const unsigned short*)v_;
    unsigned short* vT = (unsigned short*)vT_;
    __shared__ unsigned short t[32][33];
    int tx = threadIdx.x & 31, ty = threadIdx.x >> 5;
    int nb = blockIdx.x * 32, db = blockIdx.y * 32;
    int bh = blockIdx.z;
    const unsigned short* src = v + (size_t)bh * SEQ * HD;
#pragma unroll
    for (int i = 0; i < 4; ++i)
        t[ty + 8 * i][tx] = src[(size_t)(nb + ty + 8 * i) * HD + db + tx];
    __syncthreads();
    unsigned short* dst = vT + (size_t)bh * HD * SEQ;
#pragma unroll
    for (int i = 0; i < 4; ++i)
        dst[(size_t)(db + ty + 8 * i) * SEQ + nb + tx] = t[tx][ty + 8 * i];
}

// ---------------------------------------------------------------- GEMM
// C[M][Nw] = A[M][K](bf16) @ WT[Nw][K]^T(bf16) + bias, fused epilogues.
// EPI 0: scatter to q/k/v [B][H][SEQ][HD] bf16
// EPI 1: += resid, write f32
// EPI 2: gelu, write bf16
// EPI 3: += resid, write f32
template <int EPI>
__global__ __launch_bounds__(256) void gemm_k(const bf16* __restrict__ A,
                                              const bf16* __restrict__ WT,
                                              const float* __restrict__ bias,
                                              const float* __restrict__ resid,
                                              float* __restrict__ outf,
                                              bf16* __restrict__ ob0,
                                              bf16* __restrict__ ob1,
                                              bf16* __restrict__ ob2,
                                              int M, int K, int Nw) {
    int tid = threadIdx.x;
    int w = tid >> 6, l = tid & 63;
    int c = l & 15, g = l >> 4;
    int m0 = blockIdx.y * 64 + w * 16;
    int n0 = blockIdx.x * 64;

    f32x4 acc[4];
#pragma unroll
    for (int nt = 0; nt < 4; ++nt) acc[nt] = (f32x4){0.f, 0.f, 0.f, 0.f};

    const bf16* ap = A + (size_t)(m0 + c) * K + 8 * g;
    const bf16* wp = WT + (size_t)(n0 + c) * K + 8 * g;
    size_t nstep = (size_t)16 * K;
    int kcn = K >> 5;
    for (int kc = 0; kc < kcn; ++kc) {
        bf16x8 af = *(const bf16x8*)ap;
        bf16x8 b0 = *(const bf16x8*)(wp);
        bf16x8 b1 = *(const bf16x8*)(wp + nstep);
        bf16x8 b2 = *(const bf16x8*)(wp + 2 * nstep);
        bf16x8 b3 = *(const bf16x8*)(wp + 3 * nstep);
        acc[0] = mfma16(af, b0, acc[0]);
        acc[1] = mfma16(af, b1, acc[1]);
        acc[2] = mfma16(af, b2, acc[2]);
        acc[3] = mfma16(af, b3, acc[3]);
        ap += 32; wp += 32;
    }

#pragma unroll
    for (int nt = 0; nt < 4; ++nt) {
        int ntb = n0 + nt * 16;
#pragma unroll
        for (int r = 0; r < 4; ++r) {
            int m = m0 + 4 * g + r;
            int n = ntb + c;
            float val = acc[nt][r] + bias[n];
            if (EPI == 0) {
                int which = ntb / DIMD;
                int rem = ntb - which * DIMD;
                int h = rem >> 6;
                int d = (rem & 63) + c;
                int b = m >> 11, s = m & (SEQ - 1);
                bf16* dp = which == 0 ? ob0 : (which == 1 ? ob1 : ob2);
                dp[(((size_t)b * NHEADS + h) * SEQ + s) * HD + d] = __float2bfloat16(val);
            } else if (EPI == 1 || EPI == 3) {
                val += resid[(size_t)m * Nw + n];
                outf[(size_t)m * Nw + n] = val;
            } else {  // EPI 2: exact gelu
                float ge = 0.5f * val * (1.0f + erff(val * 0.70710678118654752f));
                ob0[(size_t)m * Nw + n] = __float2bfloat16(ge);
            }
        }
    }
}

// ---------------------------------------------------------------- Attention
// q,k: [BH][SEQ][HD] bf16 ; vT: [BH][HD][SEQ] bf16 ; out: [B][SEQ][DIM] bf16
__global__ __launch_bounds__(256) void attn_k(const bf16* __restrict__ q,
                                              const bf16* __restrict__ k,
                                              const bf16* __restrict__ vT,
                                              const float* __restrict__ pos,
                                              bf16* __restrict__ out) {
    __shared__ __align__(16) unsigned int P_lds[4][16][20];  // [wave][q][k/2], rows padded to 80B
    int tid = threadIdx.x;
    int w = tid >> 6, l = tid & 63;
    int lq = l & 15, g = l >> 4;
    int nq = SEQ / 64;
    int qt = blockIdx.x % nq;
    int bh = blockIdx.x / nq;
    int b = bh / NHEADS, h = bh % NHEADS;
    int qbase = qt * 64 + w * 16;
    int qrow = qbase + lq;

    const bf16* qp = q + ((size_t)bh * SEQ + qrow) * HD + 8 * g;
    bf16x8 qf0 = *(const bf16x8*)qp;
    bf16x8 qf1 = *(const bf16x8*)(qp + 32);

    const float* pq = pos + ((size_t)b * SEQ + qrow) * 3;
    float pqx = pq[0], pqy = pq[1], pqz = pq[2];

    float mrun = -INFINITY, lrun = 0.f;
    f32x4 oacc[4];
#pragma unroll
    for (int dt = 0; dt < 4; ++dt) oacc[dt] = (f32x4){0.f, 0.f, 0.f, 0.f};
    const float scale = 0.125f;

    const bf16* kbp = k + (size_t)bh * SEQ * HD + (size_t)lq * HD + 8 * g;
    const bf16* vbp = vT + (size_t)bh * HD * SEQ + (size_t)lq * SEQ + 8 * g;
    const float* posb = pos + (size_t)b * SEQ * 3;

    for (int kb = 0; kb < SEQ; kb += 32) {
        f32x4 st0 = (f32x4){0.f, 0.f, 0.f, 0.f};
        f32x4 st1 = st0;
        {
            const bf16* kp0 = kbp + (size_t)kb * HD;
            bf16x8 ka = *(const bf16x8*)kp0;
            bf16x8 kbb = *(const bf16x8*)(kp0 + 32);
            st0 = mfma16(ka, qf0, st0);
            st0 = mfma16(kbb, qf1, st0);
            const bf16* kp1 = kp0 + 16 * HD;
            ka = *(const bf16x8*)kp1;
            kbb = *(const bf16x8*)(kp1 + 32);
            st1 = mfma16(ka, qf0, st1);
            st1 = mfma16(kbb, qf1, st1);
        }
        // pos of this lane's k rows: tile0 rows kb+4g.., tile1 +16
        float kp0a[12], kp1a[12];
        const float* pk0 = posb + (size_t)(kb + 4 * g) * 3;
        *(f32x4*)&kp0a[0] = *(const f32x4*)(pk0);
        *(f32x4*)&kp0a[4] = *(const f32x4*)(pk0 + 4);
        *(f32x4*)&kp0a[8] = *(const f32x4*)(pk0 + 8);
        const float* pk1 = pk0 + 48;
        *(f32x4*)&kp1a[0] = *(const f32x4*)(pk1);
        *(f32x4*)&kp1a[4] = *(const f32x4*)(pk1 + 4);
        *(f32x4*)&kp1a[8] = *(const f32x4*)(pk1 + 8);

        float sv[8];
#pragma unroll
        for (int r = 0; r < 4; ++r) {
            float dx = pqx - kp0a[3 * r], dy = pqy - kp0a[3 * r + 1], dz = pqz - kp0a[3 * r + 2];
            float d2 = dx * dx + dy * dy + dz * dz;
            sv[r] = st0[r] * scale + __expf(-d2);
            dx = pqx - kp1a[3 * r]; dy = pqy - kp1a[3 * r + 1]; dz = pqz - kp1a[3 * r + 2];
            d2 = dx * dx + dy * dy + dz * dz;
            sv[4 + r] = st1[r] * scale + __expf(-d2);
        }
        float mloc = sv[0];
#pragma unroll
        for (int i = 1; i < 8; ++i) mloc = fmaxf(mloc, sv[i]);
        mloc = fmaxf(mloc, __shfl_xor(mloc, 16));
        mloc = fmaxf(mloc, __shfl_xor(mloc, 32));
        float mnew = fmaxf(mrun, mloc);
        float alpha = __expf(mrun - mnew);
        float p[8], ps = 0.f;
#pragma unroll
        for (int i = 0; i < 8; ++i) { p[i] = __expf(sv[i] - mnew); ps += p[i]; }
        ps += __shfl_xor(ps, 16);
        ps += __shfl_xor(ps, 32);
        lrun = lrun * alpha + ps;
        mrun = mnew;
#pragma unroll
        for (int dt = 0; dt < 4; ++dt) oacc[dt] = oacc[dt] * alpha;

        // P -> LDS (bf16, packed pairs; k index = tile*16 + 4g + r)
        P_lds[w][lq][2 * g] = pack2(p[0], p[1]);
        P_lds[w][lq][2 * g + 1] = pack2(p[2], p[3]);
        P_lds[w][lq][8 + 2 * g] = pack2(p[4], p[5]);
        P_lds[w][lq][8 + 2 * g + 1] = pack2(p[6], p[7]);

        bf16x8 pf;
        __builtin_memcpy(&pf, &P_lds[w][lq][4 * g], 16);

#pragma unroll
        for (int dt = 0; dt < 4; ++dt) {
            bf16x8 vf = *(const bf16x8*)(vbp + (size_t)dt * 16 * SEQ + kb);
            oacc[dt] = mfma16(vf, pf, oacc[dt]);
        }
    }

    float inv = 1.f / lrun;
    bf16* op = out + ((size_t)b * SEQ + qrow) * DIMD + h * HD + 4 * g;
#pragma unroll
    for (int dt = 0; dt < 4; ++dt) {
        unsigned int t2[2];
        t2[0] = pack2(oacc[dt][0] * inv, oacc[dt][1] * inv);
        t2[1] = pack2(oacc[dt][2] * inv, oacc[dt][3] * inv);
        __builtin_memcpy(op + dt * 16, t2, 8);
    }
}

// ---------------------------------------------------------------- launch
extern "C" void kernel_launch(void* const* d_in, const int* in_sizes, int n_in,
                              void* d_out, int out_size, void* d_ws, size_t ws_size,
                              hipStream_t stream) {
    const float* x      = (const float*)d_in[0];
    const float* pos    = (const float*)d_in[1];
    const float* qkv_w  = (const float*)d_in[2];
    const float* qkv_b  = (const float*)d_in[3];
    const float* proj_w = (const float*)d_in[4];
    const float* proj_b = (const float*)d_in[5];
    const float* mlp_w1 = (const float*)d_in[6];
    const float* mlp_b1 = (const float*)d_in[7];
    const float* mlp_w2 = (const float*)d_in[8];
    const float* mlp_b2 = (const float*)d_in[9];
    const float* ln1_g  = (const float*)d_in[10];
    const float* ln1_b  = (const float*)d_in[11];
    const float* ln2_g  = (const float*)d_in[12];
    const float* ln2_b  = (const float*)d_in[13];

    char* p = (char*)d_ws;
    size_t off = 0;
    auto alloc = [&](size_t bytes) {
        char* r = p + off;
        off = (off + bytes + 255) & ~(size_t)255;
        return r;
    };
    bf16* WT1 = (bf16*)alloc((size_t)1152 * 384 * 2);
    bf16* WT2 = (bf16*)alloc((size_t)384 * 384 * 2);
    bf16* WT3 = (bf16*)alloc((size_t)768 * 384 * 2);
    bf16* WT4 = (bf16*)alloc((size_t)384 * 768 * 2);
    bf16* xn  = (bf16*)alloc((size_t)NTOK * DIMD * 2);
    bf16* xn2 = (bf16*)alloc((size_t)NTOK * DIMD * 2);
    bf16* qb  = (bf16*)alloc((size_t)NTOK * DIMD * 2);
    bf16* kb  = (bf16*)alloc((size_t)NTOK * DIMD * 2);
    bf16* vb  = (bf16*)alloc((size_t)NTOK * DIMD * 2);
    bf16* vTb = (bf16*)alloc((size_t)NTOK * DIMD * 2);
    bf16* ao  = (bf16*)alloc((size_t)NTOK * DIMD * 2);
    float* x1 = (float*)alloc((size_t)NTOK * DIMD * 4);
    bf16* hh  = (bf16*)alloc((size_t)NTOK * MLPH * 2);
    if (off > ws_size) return;  // workspace too small; bail

    // weight transposes (f32 -> bf16 [N][K])
    wtrans_k<<<dim3(36, 12), 256, 0, stream>>>(qkv_w, WT1, 384, 1152);
    wtrans_k<<<dim3(12, 12), 256, 0, stream>>>(proj_w, WT2, 384, 384);
    wtrans_k<<<dim3(24, 12), 256, 0, stream>>>(mlp_w1, WT3, 384, 768);
    wtrans_k<<<dim3(12, 24), 256, 0, stream>>>(mlp_w2, WT4, 768, 384);

    // LN1
    ln_k<<<NTOK / 4, 256, 0, stream>>>(x, ln1_g, ln1_b, xn);
    // qkv GEMM -> q,k,v
    gemm_k<0><<<dim3(1152 / 64, NTOK / 64), 256, 0, stream>>>(
        xn, WT1, qkv_b, nullptr, nullptr, qb, kb, vb, NTOK, 384, 1152);
    // v -> vT
    vtrans_k<<<dim3(SEQ / 32, HD / 32, NBATCH * NHEADS), 256, 0, stream>>>(vb, vTb);
    // attention
    attn_k<<<NBATCH * NHEADS * (SEQ / 64), 256, 0, stream>>>(qb, kb, vTb, pos, ao);
    // proj + residual -> x1 (f32)
    gemm_k<1><<<dim3(384 / 64, NTOK / 64), 256, 0, stream>>>(
        ao, WT2, proj_b, x, x1, nullptr, nullptr, nullptr, NTOK, 384, 384);
    // LN2
    ln_k<<<NTOK / 4, 256, 0, stream>>>(x1, ln2_g, ln2_b, xn2);
    // mlp1 + gelu -> hh (bf16)
    gemm_k<2><<<dim3(768 / 64, NTOK / 64), 256, 0, stream>>>(
        xn2, WT3, mlp_b1, nullptr, nullptr, hh, nullptr, nullptr, NTOK, 384, 768);
    // mlp2 + residual -> out (f32)
    gemm_k<3><<<dim3(384 / 64, NTOK / 64), 256, 0, stream>>>(
        hh, WT4, mlp_b2, x1, (float*)d_out, nullptr, nullptr, nullptr, NTOK, 768, 384);
}

// Round 3
// 396.722 us; speedup vs baseline: 1.0380x; 1.0380x over previous
//
#include <hip/hip_runtime.h>
#include <hip/hip_bf16.h>
#include <math.h>

#define DIMD 384
#define NHEADS 6
#define HD 64
#define MLPH 768
#define SEQ 2048
#define NBATCH 4
#define NTOK (NBATCH*SEQ)   // 8192

typedef __hip_bfloat16 bf16;

typedef __attribute__((ext_vector_type(8))) short bf16x8;
typedef __attribute__((ext_vector_type(4))) float f32x4;

#define LOG2E 1.44269504088896340736f

static __device__ inline float fexp2(float x) { return __builtin_amdgcn_exp2f(x); }

static __device__ inline f32x4 mfma16(bf16x8 a, bf16x8 b, f32x4 c) {
    return __builtin_amdgcn_mfma_f32_16x16x32_bf16(a, b, c, 0, 0, 0);
}

static __device__ inline unsigned short bfbits(float f) {
    return __builtin_bit_cast(unsigned short, __float2bfloat16(f));
}
static __device__ inline unsigned int pack2(float lo, float hi) {
    return (unsigned int)bfbits(lo) | ((unsigned int)bfbits(hi) << 16);
}
static __device__ inline float bflo(unsigned int u) { return __builtin_bit_cast(float, u << 16); }
static __device__ inline float bfhi(unsigned int u) { return __builtin_bit_cast(float, u & 0xffff0000u); }

// ---------------------------------------------------------------- LayerNorm
__global__ __launch_bounds__(256) void ln_k(const float* __restrict__ x,
                                            const float* __restrict__ gm,
                                            const float* __restrict__ bt,
                                            bf16* __restrict__ out) {
    int row = blockIdx.x * 4 + (threadIdx.x >> 6);
    int l = threadIdx.x & 63;
    const float* xr = x + (size_t)row * DIMD;
    float v[6];
#pragma unroll
    for (int j = 0; j < 6; ++j) v[j] = xr[l + 64 * j];
    float s = 0.f, s2 = 0.f;
#pragma unroll
    for (int j = 0; j < 6; ++j) { s += v[j]; s2 += v[j] * v[j]; }
#pragma unroll
    for (int m = 1; m < 64; m <<= 1) { s += __shfl_xor(s, m); s2 += __shfl_xor(s2, m); }
    float mu = s * (1.f / DIMD);
    float var = s2 * (1.f / DIMD) - mu * mu;
    float rs = rsqrtf(var + 1e-5f);
    bf16* orow = out + (size_t)row * DIMD;
#pragma unroll
    for (int j = 0; j < 6; ++j) {
        int i = l + 64 * j;
        orow[i] = __float2bfloat16((v[j] - mu) * rs * gm[i] + bt[i]);
    }
}

// ------------------------------------------------- weight transpose + cast
__global__ __launch_bounds__(256) void wtrans_k(const float* __restrict__ W,
                                                bf16* __restrict__ WT,
                                                int K, int N) {
    __shared__ float t[32][33];
    int tx = threadIdx.x & 31, ty = threadIdx.x >> 5;
    int nb = blockIdx.x * 32, kb = blockIdx.y * 32;
#pragma unroll
    for (int i = 0; i < 4; ++i)
        t[ty + 8 * i][tx] = W[(size_t)(kb + ty + 8 * i) * N + nb + tx];
    __syncthreads();
#pragma unroll
    for (int i = 0; i < 4; ++i)
        WT[(size_t)(nb + ty + 8 * i) * K + kb + tx] = __float2bfloat16(t[tx][ty + 8 * i]);
}

// ------------------------------------------------- V transpose (per head)
__global__ __launch_bounds__(256) void vtrans_k(const bf16* __restrict__ v_,
                                                bf16* __restrict__ vT_) {
    const unsigned short* v = (const unsigned short*)v_;
    unsigned short* vT = (unsigned short*)vT_;
    __shared__ unsigned short t[32][33];
    int tx = threadIdx.x & 31, ty = threadIdx.x >> 5;
    int nb = blockIdx.x * 32, db = blockIdx.y * 32;
    int bh = blockIdx.z;
    const unsigned short* src = v + (size_t)bh * SEQ * HD;
#pragma unroll
    for (int i = 0; i < 4; ++i)
        t[ty + 8 * i][tx] = src[(size_t)(nb + ty + 8 * i) * HD + db + tx];
    __syncthreads();
    unsigned short* dst = vT + (size_t)bh * HD * SEQ;
#pragma unroll
    for (int i = 0; i < 4; ++i)
        dst[(size_t)(db + ty + 8 * i) * SEQ + nb + tx] = t[tx][ty + 8 * i];
}

// ------------------------------------------------- dist bias table
// distL[b][i][j] = log2(e) * exp(-||pos_i - pos_j||^2)   (bf16)
__global__ __launch_bounds__(256) void dist_k(const float* __restrict__ pos,
                                              bf16* __restrict__ distL) {
    int bi = blockIdx.x;               // b*SEQ + i
    int b = bi >> 11;
    const float* pi = pos + (size_t)bi * 3;
    float px = pi[0], py = pi[1], pz = pi[2];
    int j0 = threadIdx.x * 8;
    const float* pj = pos + ((size_t)b * SEQ + j0) * 3;
    float a[24];
#pragma unroll
    for (int t = 0; t < 6; ++t) *(f32x4*)&a[4 * t] = *(const f32x4*)(pj + 4 * t);
    float o8[8];
#pragma unroll
    for (int r = 0; r < 8; ++r) {
        float dx = px - a[3 * r], dy = py - a[3 * r + 1], dz = pz - a[3 * r + 2];
        float d2 = dx * dx + dy * dy + dz * dz;
        o8[r] = fexp2(-LOG2E * d2) * LOG2E;
    }
    unsigned int o[4];
#pragma unroll
    for (int t = 0; t < 4; ++t) o[t] = pack2(o8[2 * t], o8[2 * t + 1]);
    unsigned int* row = (unsigned int*)((unsigned short*)distL + (size_t)bi * SEQ);
    *(uint4*)(row + threadIdx.x * 4) = *(uint4*)o;
}

// ---------------------------------------------------------------- GEMM
// C[M][Nw] = A[M][K](bf16) @ WT[Nw][K]^T(bf16) + bias, fused epilogues.
template <int EPI, int WR>
__global__ __launch_bounds__(256) void gemm_k(const bf16* __restrict__ A,
                                              const bf16* __restrict__ WT,
                                              const float* __restrict__ bias,
                                              const float* __restrict__ resid,
                                              float* __restrict__ outf,
                                              bf16* __restrict__ ob0,
                                              bf16* __restrict__ ob1,
                                              bf16* __restrict__ ob2,
                                              int M, int K, int Nw) {
    int tid = threadIdx.x;
    int w = tid >> 6, l = tid & 63;
    int c = l & 15, g = l >> 4;
    int m0 = blockIdx.y * (64 * WR) + w * (16 * WR);
    int n0 = blockIdx.x * 64;

    f32x4 acc[WR][4];
#pragma unroll
    for (int i = 0; i < WR; ++i)
#pragma unroll
        for (int nt = 0; nt < 4; ++nt) acc[i][nt] = (f32x4){0.f, 0.f, 0.f, 0.f};

    const bf16* ap[WR];
#pragma unroll
    for (int i = 0; i < WR; ++i) ap[i] = A + (size_t)(m0 + 16 * i + c) * K + 8 * g;
    const bf16* wp = WT + (size_t)(n0 + c) * K + 8 * g;
    size_t nstep = (size_t)16 * K;
    int kcn = K >> 5;
#pragma unroll 2
    for (int kc = 0; kc < kcn; ++kc) {
        bf16x8 af[WR];
#pragma unroll
        for (int i = 0; i < WR; ++i) af[i] = *(const bf16x8*)ap[i];
        bf16x8 b0 = *(const bf16x8*)(wp);
        bf16x8 b1 = *(const bf16x8*)(wp + nstep);
        bf16x8 b2 = *(const bf16x8*)(wp + 2 * nstep);
        bf16x8 b3 = *(const bf16x8*)(wp + 3 * nstep);
#pragma unroll
        for (int i = 0; i < WR; ++i) {
            acc[i][0] = mfma16(af[i], b0, acc[i][0]);
            acc[i][1] = mfma16(af[i], b1, acc[i][1]);
            acc[i][2] = mfma16(af[i], b2, acc[i][2]);
            acc[i][3] = mfma16(af[i], b3, acc[i][3]);
        }
#pragma unroll
        for (int i = 0; i < WR; ++i) ap[i] += 32;
        wp += 32;
    }

#pragma unroll
    for (int i = 0; i < WR; ++i) {
#pragma unroll
        for (int nt = 0; nt < 4; ++nt) {
            int ntb = n0 + nt * 16;
#pragma unroll
            for (int r = 0; r < 4; ++r) {
                int m = m0 + 16 * i + 4 * g + r;
                int n = ntb + c;
                float val = acc[i][nt][r] + bias[n];
                if (EPI == 0) {
                    int which = ntb / DIMD;
                    int rem = ntb - which * DIMD;
                    int h = rem >> 6;
                    int d = (rem & 63) + c;
                    int b = m >> 11, s = m & (SEQ - 1);
                    bf16* dp = which == 0 ? ob0 : (which == 1 ? ob1 : ob2);
                    dp[(((size_t)b * NHEADS + h) * SEQ + s) * HD + d] = __float2bfloat16(val);
                } else if (EPI == 1 || EPI == 3) {
                    val += resid[(size_t)m * Nw + n];
                    outf[(size_t)m * Nw + n] = val;
                } else {
                    float ge = 0.5f * val * (1.0f + erff(val * 0.70710678118654752f));
                    ob0[(size_t)m * Nw + n] = __float2bfloat16(ge);
                }
            }
        }
    }
}

// ---------------------------------------------------------------- Attention
// q,k: [BH][SEQ][HD] bf16 ; vT: [BH][HD][SEQ] bf16 ; distL: [B][SEQ][SEQ] bf16
// out: [B][SEQ][DIM] bf16.  Fixed-max (m=0) softmax: scores are bounded small.
template <int TAB>
__global__ __launch_bounds__(256) void attn_k(const bf16* __restrict__ q,
                                              const bf16* __restrict__ k,
                                              const bf16* __restrict__ vT,
                                              const float* __restrict__ pos,
                                              const bf16* __restrict__ distL,
                                              bf16* __restrict__ out) {
    __shared__ __align__(16) unsigned int P_lds[4][16][21];  // odd stride: no 4-way banks
    int tid = threadIdx.x;
    int w = tid >> 6, l = tid & 63;
    int lq = l & 15, g = l >> 4;
    int nq = SEQ / 64;
    int qt = blockIdx.x % nq;
    int bh = blockIdx.x / nq;
    int b = bh / NHEADS, h = bh % NHEADS;
    int qrow = qt * 64 + w * 16 + lq;

    const bf16* qp = q + ((size_t)bh * SEQ + qrow) * HD + 8 * g;
    bf16x8 qf0 = *(const bf16x8*)qp;
    bf16x8 qf1 = *(const bf16x8*)(qp + 32);

    const float SC2 = 0.125f * LOG2E;

    const bf16* kbase = k + (size_t)bh * SEQ * HD + (size_t)lq * HD + 8 * g;
    const bf16* vbase = vT + (size_t)bh * HD * SEQ + (size_t)lq * SEQ + 8 * g;
    const unsigned short* drow =
        (const unsigned short*)distL + ((size_t)b * SEQ + qrow) * SEQ + 4 * g;
    const float* posb = pos + (size_t)b * SEQ * 3;
    float pqx = 0.f, pqy = 0.f, pqz = 0.f;
    if (!TAB) {
        const float* pq = pos + ((size_t)b * SEQ + qrow) * 3;
        pqx = pq[0]; pqy = pq[1]; pqz = pq[2];
    }

    float lrun = 0.f;
    f32x4 oacc[4];
#pragma unroll
    for (int dt = 0; dt < 4; ++dt) oacc[dt] = (f32x4){0.f, 0.f, 0.f, 0.f};

    auto loadK = [&](int kb, bf16x8& x0, bf16x8& x1, bf16x8& x2, bf16x8& x3) {
        const bf16* kp0 = kbase + (size_t)kb * HD;
        x0 = *(const bf16x8*)kp0;
        x1 = *(const bf16x8*)(kp0 + 32);
        const bf16* kp1 = kp0 + 16 * HD;
        x2 = *(const bf16x8*)kp1;
        x3 = *(const bf16x8*)(kp1 + 32);
    };
    auto loadV = [&](int kb, bf16x8& x0, bf16x8& x1, bf16x8& x2, bf16x8& x3) {
        x0 = *(const bf16x8*)(vbase + kb);
        x1 = *(const bf16x8*)(vbase + 16 * SEQ + kb);
        x2 = *(const bf16x8*)(vbase + 32 * SEQ + kb);
        x3 = *(const bf16x8*)(vbase + 48 * SEQ + kb);
    };
    auto loadD = [&](int kb, uint2& d0, uint2& d1) {
        d0 = *(const uint2*)(drow + kb);
        d1 = *(const uint2*)(drow + kb + 16);
    };

    // prefetch tile 0
    bf16x8 ck0, ck1, ck2, ck3, cv0, cv1, cv2, cv3;
    uint2 cd0 = {0, 0}, cd1 = {0, 0};
    loadK(0, ck0, ck1, ck2, ck3);
    loadV(0, cv0, cv1, cv2, cv3);
    if (TAB) loadD(0, cd0, cd1);

    for (int kb = 0; kb < SEQ; kb += 32) {
        int kn = (kb + 32 < SEQ) ? kb + 32 : 0;   // last-iter prefetch is harmless
        bf16x8 nk0, nk1, nk2, nk3, nv0, nv1, nv2, nv3;
        uint2 nd0 = {0, 0}, nd1 = {0, 0};
        loadK(kn, nk0, nk1, nk2, nk3);
        loadV(kn, nv0, nv1, nv2, nv3);
        if (TAB) loadD(kn, nd0, nd1);

        f32x4 z = (f32x4){0.f, 0.f, 0.f, 0.f};
        f32x4 st0 = mfma16(ck0, qf0, z);
        st0 = mfma16(ck1, qf1, st0);
        f32x4 st1 = mfma16(ck2, qf0, z);
        st1 = mfma16(ck3, qf1, st1);

        float dl[8];
        if (TAB) {
            dl[0] = bflo(cd0.x); dl[1] = bfhi(cd0.x);
            dl[2] = bflo(cd0.y); dl[3] = bfhi(cd0.y);
            dl[4] = bflo(cd1.x); dl[5] = bfhi(cd1.x);
            dl[6] = bflo(cd1.y); dl[7] = bfhi(cd1.y);
        } else {
            float kp0a[12], kp1a[12];
            const float* pk0 = posb + (size_t)(kb + 4 * g) * 3;
            *(f32x4*)&kp0a[0] = *(const f32x4*)(pk0);
            *(f32x4*)&kp0a[4] = *(const f32x4*)(pk0 + 4);
            *(f32x4*)&kp0a[8] = *(const f32x4*)(pk0 + 8);
            const float* pk1 = pk0 + 48;
            *(f32x4*)&kp1a[0] = *(const f32x4*)(pk1);
            *(f32x4*)&kp1a[4] = *(const f32x4*)(pk1 + 4);
            *(f32x4*)&kp1a[8] = *(const f32x4*)(pk1 + 8);
#pragma unroll
            for (int r = 0; r < 4; ++r) {
                float dx = pqx - kp0a[3 * r], dy = pqy - kp0a[3 * r + 1], dz = pqz - kp0a[3 * r + 2];
                float d2 = dx * dx + dy * dy + dz * dz;
                dl[r] = fexp2(-LOG2E * d2) * LOG2E;
                dx = pqx - kp1a[3 * r]; dy = pqy - kp1a[3 * r + 1]; dz = pqz - kp1a[3 * r + 2];
                d2 = dx * dx + dy * dy + dz * dz;
                dl[4 + r] = fexp2(-LOG2E * d2) * LOG2E;
            }
        }

        float p[8], ps = 0.f;
#pragma unroll
        for (int i = 0; i < 4; ++i) p[i] = fexp2(st0[i] * SC2 + dl[i]);
#pragma unroll
        for (int i = 0; i < 4; ++i) p[4 + i] = fexp2(st1[i] * SC2 + dl[4 + i]);
#pragma unroll
        for (int i = 0; i < 8; ++i) ps += p[i];
        ps += __shfl_xor(ps, 16);
        ps += __shfl_xor(ps, 32);
        lrun += ps;

        P_lds[w][lq][2 * g] = pack2(p[0], p[1]);
        P_lds[w][lq][2 * g + 1] = pack2(p[2], p[3]);
        P_lds[w][lq][8 + 2 * g] = pack2(p[4], p[5]);
        P_lds[w][lq][8 + 2 * g + 1] = pack2(p[6], p[7]);

        bf16x8 pf;
        __builtin_memcpy(&pf, &P_lds[w][lq][4 * g], 16);

        oacc[0] = mfma16(cv0, pf, oacc[0]);
        oacc[1] = mfma16(cv1, pf, oacc[1]);
        oacc[2] = mfma16(cv2, pf, oacc[2]);
        oacc[3] = mfma16(cv3, pf, oacc[3]);

        ck0 = nk0; ck1 = nk1; ck2 = nk2; ck3 = nk3;
        cv0 = nv0; cv1 = nv1; cv2 = nv2; cv3 = nv3;
        cd0 = nd0; cd1 = nd1;
    }

    float inv = 1.f / lrun;
    bf16* op = out + ((size_t)b * SEQ + qrow) * DIMD + h * HD + 4 * g;
#pragma unroll
    for (int dt = 0; dt < 4; ++dt) {
        unsigned int t2[2];
        t2[0] = pack2(oacc[dt][0] * inv, oacc[dt][1] * inv);
        t2[1] = pack2(oacc[dt][2] * inv, oacc[dt][3] * inv);
        __builtin_memcpy(op + dt * 16, t2, 8);
    }
}

// ---------------------------------------------------------------- launch
extern "C" void kernel_launch(void* const* d_in, const int* in_sizes, int n_in,
                              void* d_out, int out_size, void* d_ws, size_t ws_size,
                              hipStream_t stream) {
    const float* x      = (const float*)d_in[0];
    const float* pos    = (const float*)d_in[1];
    const float* qkv_w  = (const float*)d_in[2];
    const float* qkv_b  = (const float*)d_in[3];
    const float* proj_w = (const float*)d_in[4];
    const float* proj_b = (const float*)d_in[5];
    const float* mlp_w1 = (const float*)d_in[6];
    const float* mlp_b1 = (const float*)d_in[7];
    const float* mlp_w2 = (const float*)d_in[8];
    const float* mlp_b2 = (const float*)d_in[9];
    const float* ln1_g  = (const float*)d_in[10];
    const float* ln1_b  = (const float*)d_in[11];
    const float* ln2_g  = (const float*)d_in[12];
    const float* ln2_b  = (const float*)d_in[13];

    char* p = (char*)d_ws;
    size_t off = 0;
    auto alloc = [&](size_t bytes) {
        char* r = p + off;
        off = (off + bytes + 255) & ~(size_t)255;
        return r;
    };
    bf16* WT1 = (bf16*)alloc((size_t)1152 * 384 * 2);
    bf16* WT2 = (bf16*)alloc((size_t)384 * 384 * 2);
    bf16* WT3 = (bf16*)alloc((size_t)384 * 768 * 2);
    bf16* WT4 = (bf16*)alloc((size_t)768 * 384 * 2);
    bf16* xn  = (bf16*)alloc((size_t)NTOK * DIMD * 2);
    bf16* xn2 = (bf16*)alloc((size_t)NTOK * DIMD * 2);
    bf16* qb  = (bf16*)alloc((size_t)NTOK * DIMD * 2);
    bf16* kb  = (bf16*)alloc((size_t)NTOK * DIMD * 2);
    bf16* vb  = (bf16*)alloc((size_t)NTOK * DIMD * 2);
    bf16* vTb = (bf16*)alloc((size_t)NTOK * DIMD * 2);
    bf16* ao  = (bf16*)alloc((size_t)NTOK * DIMD * 2);
    float* x1 = (float*)alloc((size_t)NTOK * DIMD * 4);
    bf16* hh  = (bf16*)alloc((size_t)NTOK * MLPH * 2);
    if (off > ws_size) return;  // base workspace too small; cannot run
    bf16* dtab = (bf16*)alloc((size_t)NBATCH * SEQ * SEQ * 2);  // 32 MiB
    bool tab = (off <= ws_size);

    wtrans_k<<<dim3(36, 12), 256, 0, stream>>>(qkv_w, WT1, 384, 1152);
    wtrans_k<<<dim3(12, 12), 256, 0, stream>>>(proj_w, WT2, 384, 384);
    wtrans_k<<<dim3(24, 12), 256, 0, stream>>>(mlp_w1, WT3, 384, 768);
    wtrans_k<<<dim3(12, 24), 256, 0, stream>>>(mlp_w2, WT4, 768, 384);

    if (tab) dist_k<<<NBATCH * SEQ, 256, 0, stream>>>(pos, dtab);

    ln_k<<<NTOK / 4, 256, 0, stream>>>(x, ln1_g, ln1_b, xn);
    gemm_k<0, 2><<<dim3(1152 / 64, NTOK / 128), 256, 0, stream>>>(
        xn, WT1, qkv_b, nullptr, nullptr, qb, kb, vb, NTOK, 384, 1152);
    vtrans_k<<<dim3(SEQ / 32, HD / 32, NBATCH * NHEADS), 256, 0, stream>>>(vb, vTb);
    if (tab)
        attn_k<1><<<NBATCH * NHEADS * (SEQ / 64), 256, 0, stream>>>(qb, kb, vTb, pos, dtab, ao);
    else
        attn_k<0><<<NBATCH * NHEADS * (SEQ / 64), 256, 0, stream>>>(qb, kb, vTb, pos, dtab, ao);
    gemm_k<1, 1><<<dim3(384 / 64, NTOK / 64), 256, 0, stream>>>(
        ao, WT2, proj_b, x, x1, nullptr, nullptr, nullptr, NTOK, 384, 384);
    ln_k<<<NTOK / 4, 256, 0, stream>>>(x1, ln2_g, ln2_b, xn2);
    gemm_k<2, 2><<<dim3(768 / 64, NTOK / 128), 256, 0, stream>>>(
        xn2, WT3, mlp_b1, nullptr, nullptr, hh, nullptr, nullptr, NTOK, 384, 768);
    gemm_k<3, 1><<<dim3(384 / 64, NTOK / 64), 256, 0, stream>>>(
        hh, WT4, mlp_b2, x1, (float*)d_out, nullptr, nullptr, nullptr, NTOK, 768, 384);
}

// Round 4
// 270.056 us; speedup vs baseline: 1.5249x; 1.4690x over previous
//
#include <hip/hip_runtime.h>
#include <hip/hip_bf16.h>
#include <math.h>

#define DIMD 384
#define NHEADS 6
#define HD 64
#define MLPH 768
#define SEQ 2048
#define NBATCH 4
#define NTOK (NBATCH*SEQ)   // 8192

typedef __hip_bfloat16 bf16;

typedef __attribute__((ext_vector_type(8))) short bf16x8;
typedef __attribute__((ext_vector_type(4))) float f32x4;

#define LOG2E 1.44269504088896340736f

static __device__ inline float fexp2(float x) { return __builtin_amdgcn_exp2f(x); }

static __device__ inline f32x4 mfma16(bf16x8 a, bf16x8 b, f32x4 c) {
    return __builtin_amdgcn_mfma_f32_16x16x32_bf16(a, b, c, 0, 0, 0);
}

static __device__ inline unsigned short bfbits(float f) {
    return __builtin_bit_cast(unsigned short, __float2bfloat16(f));
}
static __device__ inline unsigned int pack2(float lo, float hi) {
    return (unsigned int)bfbits(lo) | ((unsigned int)bfbits(hi) << 16);
}
static __device__ inline float bflo(unsigned int u) { return __builtin_bit_cast(float, u << 16); }
static __device__ inline float bfhi(unsigned int u) { return __builtin_bit_cast(float, u & 0xffff0000u); }

// async global->LDS, 16B per lane. LDS dest is wave-uniform base + lane*16 (linear).
static __device__ inline void gld16(const void* g, void* l) {
    __builtin_amdgcn_global_load_lds(
        (const __attribute__((address_space(1))) unsigned int*)g,
        (__attribute__((address_space(3))) unsigned int*)l, 16, 0, 0);
}

// ---------------------------------------------------------------- LayerNorm
__global__ __launch_bounds__(256) void ln_k(const float* __restrict__ x,
                                            const float* __restrict__ gm,
                                            const float* __restrict__ bt,
                                            bf16* __restrict__ out) {
    int row = blockIdx.x * 4 + (threadIdx.x >> 6);
    int l = threadIdx.x & 63;
    const float* xr = x + (size_t)row * DIMD;
    float v[6];
#pragma unroll
    for (int j = 0; j < 6; ++j) v[j] = xr[l + 64 * j];
    float s = 0.f, s2 = 0.f;
#pragma unroll
    for (int j = 0; j < 6; ++j) { s += v[j]; s2 += v[j] * v[j]; }
#pragma unroll
    for (int m = 1; m < 64; m <<= 1) { s += __shfl_xor(s, m); s2 += __shfl_xor(s2, m); }
    float mu = s * (1.f / DIMD);
    float var = s2 * (1.f / DIMD) - mu * mu;
    float rs = rsqrtf(var + 1e-5f);
    bf16* orow = out + (size_t)row * DIMD;
#pragma unroll
    for (int j = 0; j < 6; ++j) {
        int i = l + 64 * j;
        orow[i] = __float2bfloat16((v[j] - mu) * rs * gm[i] + bt[i]);
    }
}

// ------------------------------------------------- weight transpose + cast
__global__ __launch_bounds__(256) void wtrans_k(const float* __restrict__ W,
                                                bf16* __restrict__ WT,
                                                int K, int N) {
    __shared__ float t[32][33];
    int tx = threadIdx.x & 31, ty = threadIdx.x >> 5;
    int nb = blockIdx.x * 32, kb = blockIdx.y * 32;
#pragma unroll
    for (int i = 0; i < 4; ++i)
        t[ty + 8 * i][tx] = W[(size_t)(kb + ty + 8 * i) * N + nb + tx];
    __syncthreads();
#pragma unroll
    for (int i = 0; i < 4; ++i)
        WT[(size_t)(nb + ty + 8 * i) * K + kb + tx] = __float2bfloat16(t[tx][ty + 8 * i]);
}

// ------------------------------------------------- V transpose (per head)
__global__ __launch_bounds__(256) void vtrans_k(const bf16* __restrict__ v_,
                                                bf16* __restrict__ vT_) {
    const unsigned short* v = (const unsigned short*)v_;
    unsigned short* vT = (unsigned short*)vT_;
    __shared__ unsigned short t[32][33];
    int tx = threadIdx.x & 31, ty = threadIdx.x >> 5;
    int nb = blockIdx.x * 32, db = blockIdx.y * 32;
    int bh = blockIdx.z;
    const unsigned short* src = v + (size_t)bh * SEQ * HD;
#pragma unroll
    for (int i = 0; i < 4; ++i)
        t[ty + 8 * i][tx] = src[(size_t)(nb + ty + 8 * i) * HD + db + tx];
    __syncthreads();
    unsigned short* dst = vT + (size_t)bh * HD * SEQ;
#pragma unroll
    for (int i = 0; i < 4; ++i)
        dst[(size_t)(db + ty + 8 * i) * SEQ + nb + tx] = t[tx][ty + 8 * i];
}

// ------------------------------------------------- dist bias table
// distL[b][i][j] = log2(e) * exp(-||pos_i - pos_j||^2)   (bf16)
__global__ __launch_bounds__(256) void dist_k(const float* __restrict__ pos,
                                              bf16* __restrict__ distL) {
    int bi = blockIdx.x;               // b*SEQ + i
    int b = bi >> 11;
    const float* pi = pos + (size_t)bi * 3;
    float px = pi[0], py = pi[1], pz = pi[2];
    int j0 = threadIdx.x * 8;
    const float* pj = pos + ((size_t)b * SEQ + j0) * 3;
    float a[24];
#pragma unroll
    for (int t = 0; t < 6; ++t) *(f32x4*)&a[4 * t] = *(const f32x4*)(pj + 4 * t);
    float o8[8];
#pragma unroll
    for (int r = 0; r < 8; ++r) {
        float dx = px - a[3 * r], dy = py - a[3 * r + 1], dz = pz - a[3 * r + 2];
        float d2 = dx * dx + dy * dy + dz * dz;
        o8[r] = fexp2(-LOG2E * d2) * LOG2E;
    }
    unsigned int o[4];
#pragma unroll
    for (int t = 0; t < 4; ++t) o[t] = pack2(o8[2 * t], o8[2 * t + 1]);
    unsigned int* row = (unsigned int*)((unsigned short*)distL + (size_t)bi * SEQ);
    *(uint4*)(row + threadIdx.x * 4) = *(uint4*)o;
}

// ---------------------------------------------------------------- GEMM
template <int EPI, int WR>
__global__ __launch_bounds__(256) void gemm_k(const bf16* __restrict__ A,
                                              const bf16* __restrict__ WT,
                                              const float* __restrict__ bias,
                                              const float* __restrict__ resid,
                                              float* __restrict__ outf,
                                              bf16* __restrict__ ob0,
                                              bf16* __restrict__ ob1,
                                              bf16* __restrict__ ob2,
                                              int M, int K, int Nw) {
    int tid = threadIdx.x;
    int w = tid >> 6, l = tid & 63;
    int c = l & 15, g = l >> 4;
    int m0 = blockIdx.y * (64 * WR) + w * (16 * WR);
    int n0 = blockIdx.x * 64;

    f32x4 acc[WR][4];
#pragma unroll
    for (int i = 0; i < WR; ++i)
#pragma unroll
        for (int nt = 0; nt < 4; ++nt) acc[i][nt] = (f32x4){0.f, 0.f, 0.f, 0.f};

    const bf16* ap[WR];
#pragma unroll
    for (int i = 0; i < WR; ++i) ap[i] = A + (size_t)(m0 + 16 * i + c) * K + 8 * g;
    const bf16* wp = WT + (size_t)(n0 + c) * K + 8 * g;
    size_t nstep = (size_t)16 * K;
    int kcn = K >> 5;
#pragma unroll 2
    for (int kc = 0; kc < kcn; ++kc) {
        bf16x8 af[WR];
#pragma unroll
        for (int i = 0; i < WR; ++i) af[i] = *(const bf16x8*)ap[i];
        bf16x8 b0 = *(const bf16x8*)(wp);
        bf16x8 b1 = *(const bf16x8*)(wp + nstep);
        bf16x8 b2 = *(const bf16x8*)(wp + 2 * nstep);
        bf16x8 b3 = *(const bf16x8*)(wp + 3 * nstep);
#pragma unroll
        for (int i = 0; i < WR; ++i) {
            acc[i][0] = mfma16(af[i], b0, acc[i][0]);
            acc[i][1] = mfma16(af[i], b1, acc[i][1]);
            acc[i][2] = mfma16(af[i], b2, acc[i][2]);
            acc[i][3] = mfma16(af[i], b3, acc[i][3]);
        }
#pragma unroll
        for (int i = 0; i < WR; ++i) ap[i] += 32;
        wp += 32;
    }

#pragma unroll
    for (int i = 0; i < WR; ++i) {
#pragma unroll
        for (int nt = 0; nt < 4; ++nt) {
            int ntb = n0 + nt * 16;
#pragma unroll
            for (int r = 0; r < 4; ++r) {
                int m = m0 + 16 * i + 4 * g + r;
                int n = ntb + c;
                float val = acc[i][nt][r] + bias[n];
                if (EPI == 0) {
                    int which = ntb / DIMD;
                    int rem = ntb - which * DIMD;
                    int h = rem >> 6;
                    int d = (rem & 63) + c;
                    int b = m >> 11, s = m & (SEQ - 1);
                    bf16* dp = which == 0 ? ob0 : (which == 1 ? ob1 : ob2);
                    dp[(((size_t)b * NHEADS + h) * SEQ + s) * HD + d] = __float2bfloat16(val);
                } else if (EPI == 1 || EPI == 3) {
                    val += resid[(size_t)m * Nw + n];
                    outf[(size_t)m * Nw + n] = val;
                } else {
                    float ge = 0.5f * val * (1.0f + erff(val * 0.70710678118654752f));
                    ob0[(size_t)m * Nw + n] = __float2bfloat16(ge);
                }
            }
        }
    }
}

// ---------------------------------------------------------------- Attention
// LDS-staged, double-buffered, KBLK=64. XOR chunk-swizzle (16B chunks within
// 128B rows): LDS[row][c] holds global chunk (c ^ (row&7)) — applied on the
// staging SOURCE address (dest linear per global_load_lds), inverted on reads.
__global__ __launch_bounds__(256) void attn_k(const bf16* __restrict__ q,
                                              const bf16* __restrict__ k,
                                              const bf16* __restrict__ vT,
                                              const bf16* __restrict__ distL,
                                              bf16* __restrict__ out) {
    __shared__ __align__(16) char Kls[2][8192];   // K  [64 k-rows][64 d]
    __shared__ __align__(16) char Vls[2][8192];   // V^T[64 d-rows][64 k]
    __shared__ __align__(16) char Dls[2][8192];   // D  [64 q-rows][64 k]
    __shared__ __align__(16) unsigned int P_lds[4][16][20];

    int tid = threadIdx.x;
    int w = tid >> 6, l = tid & 63;
    int lq = l & 15, g = l >> 4;
    int qt = blockIdx.x & 31;            // SEQ/64 = 32 q-tiles
    int bh = blockIdx.x >> 5;
    int b = bh / NHEADS, h = bh % NHEADS;
    int qrow = qt * 64 + w * 16 + lq;

    const bf16* qp = q + ((size_t)bh * SEQ + qrow) * HD + 8 * g;
    bf16x8 qf0 = *(const bf16x8*)qp;
    bf16x8 qf1 = *(const bf16x8*)(qp + 32);

    const char* kgb = (const char*)(k + (size_t)bh * SEQ * HD);
    const char* vgb = (const char*)(vT + (size_t)bh * HD * SEQ);
    const char* dgb = (const char*)(distL + ((size_t)b * SEQ + qt * 64) * SEQ);

    const float SC2 = 0.125f * LOG2E;
    float lrun = 0.f;
    f32x4 oacc[4];
#pragma unroll
    for (int dt = 0; dt < 4; ++dt) oacc[dt] = (f32x4){0.f, 0.f, 0.f, 0.f};

    auto stage = [&](int t, int bi) {
#pragma unroll
        for (int p = 0; p < 2; ++p) {
            int chunk = p * 256 + tid;        // 512 x 16B per 8KB buffer
            int r = chunk >> 3, c = chunk & 7;
            int cc = (c ^ (r & 7)) << 4;      // pre-swizzled source chunk
            gld16(kgb + (size_t)t * 8192 + r * 128 + cc, &Kls[bi][chunk * 16]);
            gld16(vgb + (size_t)r * 4096 + t * 128 + cc, &Vls[bi][chunk * 16]);
            gld16(dgb + (size_t)r * 4096 + t * 128 + cc, &Dls[bi][chunk * 16]);
        }
    };

    stage(0, 0);

    int swq = lq & 7;                    // row&7 for all our read rows
    for (int t = 0; t < 32; ++t) {
        int bi = t & 1;
        __syncthreads();                 // drains vmcnt: buf[bi] ready; prev reads done
        if (t + 1 < 32) stage(t + 1, bi ^ 1);

        // QK^T: S^T fragments for 4 k-subtiles of 16
        f32x4 st[4];
#pragma unroll
        for (int s = 0; s < 4; ++s) {
            int ro = (16 * s + lq) * 128;
            bf16x8 klo, khi;
            __builtin_memcpy(&klo, &Kls[bi][ro + ((g ^ swq) << 4)], 16);
            __builtin_memcpy(&khi, &Kls[bi][ro + (((4 + g) ^ swq) << 4)], 16);
            f32x4 z = (f32x4){0.f, 0.f, 0.f, 0.f};
            st[s] = mfma16(klo, qf0, z);
            st[s] = mfma16(khi, qf1, st[s]);
        }

        int rowd = (w * 16 + lq) * 128;
#pragma unroll
        for (int m = 0; m < 2; ++m) {
            uint2 dlo = *(const uint2*)&Dls[bi][rowd + (((4 * m + (g >> 1)) ^ swq) << 4) + (g & 1) * 8];
            uint2 dhi = *(const uint2*)&Dls[bi][rowd + (((4 * m + 2 + (g >> 1)) ^ swq) << 4) + (g & 1) * 8];
            f32x4 s0v = st[2 * m], s1v = st[2 * m + 1];
            float p[8];
            p[0] = fexp2(s0v[0] * SC2 + bflo(dlo.x));
            p[1] = fexp2(s0v[1] * SC2 + bfhi(dlo.x));
            p[2] = fexp2(s0v[2] * SC2 + bflo(dlo.y));
            p[3] = fexp2(s0v[3] * SC2 + bfhi(dlo.y));
            p[4] = fexp2(s1v[0] * SC2 + bflo(dhi.x));
            p[5] = fexp2(s1v[1] * SC2 + bfhi(dhi.x));
            p[6] = fexp2(s1v[2] * SC2 + bflo(dhi.y));
            p[7] = fexp2(s1v[3] * SC2 + bfhi(dhi.y));
            float ps = 0.f;
#pragma unroll
            for (int i = 0; i < 8; ++i) ps += p[i];
            ps += __shfl_xor(ps, 16);
            ps += __shfl_xor(ps, 32);
            lrun += ps;

            // repack P (k within this 32-half) to standard B-frag layout via LDS
            P_lds[w][lq][2 * g] = pack2(p[0], p[1]);
            P_lds[w][lq][2 * g + 1] = pack2(p[2], p[3]);
            P_lds[w][lq][8 + 2 * g] = pack2(p[4], p[5]);
            P_lds[w][lq][8 + 2 * g + 1] = pack2(p[6], p[7]);
            bf16x8 pf;
            __builtin_memcpy(&pf, &P_lds[w][lq][4 * g], 16);

#pragma unroll
            for (int dt = 0; dt < 4; ++dt) {
                int rv = (16 * dt + lq) * 128;
                bf16x8 vf;
                __builtin_memcpy(&vf, &Vls[bi][rv + (((4 * m + g) ^ swq) << 4)], 16);
                oacc[dt] = mfma16(vf, pf, oacc[dt]);
            }
        }
    }

    float inv = 1.f / lrun;
    bf16* op = out + ((size_t)b * SEQ + qrow) * DIMD + h * HD + 4 * g;
#pragma unroll
    for (int dt = 0; dt < 4; ++dt) {
        unsigned int t2[2];
        t2[0] = pack2(oacc[dt][0] * inv, oacc[dt][1] * inv);
        t2[1] = pack2(oacc[dt][2] * inv, oacc[dt][3] * inv);
        __builtin_memcpy(op + dt * 16, t2, 8);
    }
}

// ---------------------------------------------------------------- launch
extern "C" void kernel_launch(void* const* d_in, const int* in_sizes, int n_in,
                              void* d_out, int out_size, void* d_ws, size_t ws_size,
                              hipStream_t stream) {
    const float* x      = (const float*)d_in[0];
    const float* pos    = (const float*)d_in[1];
    const float* qkv_w  = (const float*)d_in[2];
    const float* qkv_b  = (const float*)d_in[3];
    const float* proj_w = (const float*)d_in[4];
    const float* proj_b = (const float*)d_in[5];
    const float* mlp_w1 = (const float*)d_in[6];
    const float* mlp_b1 = (const float*)d_in[7];
    const float* mlp_w2 = (const float*)d_in[8];
    const float* mlp_b2 = (const float*)d_in[9];
    const float* ln1_g  = (const float*)d_in[10];
    const float* ln1_b  = (const float*)d_in[11];
    const float* ln2_g  = (const float*)d_in[12];
    const float* ln2_b  = (const float*)d_in[13];

    char* p = (char*)d_ws;
    size_t off = 0;
    auto alloc = [&](size_t bytes) {
        char* r = p + off;
        off = (off + bytes + 255) & ~(size_t)255;
        return r;
    };
    bf16* WT1 = (bf16*)alloc((size_t)1152 * 384 * 2);
    bf16* WT2 = (bf16*)alloc((size_t)384 * 384 * 2);
    bf16* WT3 = (bf16*)alloc((size_t)384 * 768 * 2);
    bf16* WT4 = (bf16*)alloc((size_t)768 * 384 * 2);
    bf16* xn  = (bf16*)alloc((size_t)NTOK * DIMD * 2);
    bf16* xn2 = (bf16*)alloc((size_t)NTOK * DIMD * 2);
    bf16* qb  = (bf16*)alloc((size_t)NTOK * DIMD * 2);
    bf16* kb  = (bf16*)alloc((size_t)NTOK * DIMD * 2);
    bf16* vb  = (bf16*)alloc((size_t)NTOK * DIMD * 2);
    bf16* vTb = (bf16*)alloc((size_t)NTOK * DIMD * 2);
    bf16* ao  = (bf16*)alloc((size_t)NTOK * DIMD * 2);
    float* x1 = (float*)alloc((size_t)NTOK * DIMD * 4);
    bf16* hh  = (bf16*)alloc((size_t)NTOK * MLPH * 2);
    bf16* dtab = (bf16*)alloc((size_t)NBATCH * SEQ * SEQ * 2);  // 32 MiB
    if (off > ws_size) return;  // workspace too small; cannot run

    wtrans_k<<<dim3(36, 12), 256, 0, stream>>>(qkv_w, WT1, 384, 1152);
    wtrans_k<<<dim3(12, 12), 256, 0, stream>>>(proj_w, WT2, 384, 384);
    wtrans_k<<<dim3(24, 12), 256, 0, stream>>>(mlp_w1, WT3, 384, 768);
    wtrans_k<<<dim3(12, 24), 256, 0, stream>>>(mlp_w2, WT4, 768, 384);

    dist_k<<<NBATCH * SEQ, 256, 0, stream>>>(pos, dtab);

    ln_k<<<NTOK / 4, 256, 0, stream>>>(x, ln1_g, ln1_b, xn);
    gemm_k<0, 2><<<dim3(1152 / 64, NTOK / 128), 256, 0, stream>>>(
        xn, WT1, qkv_b, nullptr, nullptr, qb, kb, vb, NTOK, 384, 1152);
    vtrans_k<<<dim3(SEQ / 32, HD / 32, NBATCH * NHEADS), 256, 0, stream>>>(vb, vTb);
    attn_k<<<NBATCH * NHEADS * (SEQ / 64), 256, 0, stream>>>(qb, kb, vTb, dtab, ao);
    gemm_k<1, 1><<<dim3(384 / 64, NTOK / 64), 256, 0, stream>>>(
        ao, WT2, proj_b, x, x1, nullptr, nullptr, nullptr, NTOK, 384, 384);
    ln_k<<<NTOK / 4, 256, 0, stream>>>(x1, ln2_g, ln2_b, xn2);
    gemm_k<2, 2><<<dim3(768 / 64, NTOK / 128), 256, 0, stream>>>(
        xn2, WT3, mlp_b1, nullptr, nullptr, hh, nullptr, nullptr, NTOK, 384, 768);
    gemm_k<3, 1><<<dim3(384 / 64, NTOK / 64), 256, 0, stream>>>(
        hh, WT4, mlp_b2, x1, (float*)d_out, nullptr, nullptr, nullptr, NTOK, 768, 384);
}

// Round 5
// 154.137 us; speedup vs baseline: 2.6717x; 1.7521x over previous
//
#include <hip/hip_runtime.h>
#include <hip/hip_bf16.h>
#include <math.h>

#define DIMD 384
#define NHEADS 6
#define HD 64
#define MLPH 768
#define SEQ 2048
#define NBATCH 4
#define NTOK (NBATCH*SEQ)   // 8192

typedef __hip_bfloat16 bf16;

typedef __attribute__((ext_vector_type(8))) short bf16x8;
typedef __attribute__((ext_vector_type(4))) float f32x4;

#define LOG2E 1.44269504088896340736f

static __device__ inline float fexp2(float x) { return __builtin_amdgcn_exp2f(x); }

static __device__ inline f32x4 mfma16(bf16x8 a, bf16x8 b, f32x4 c) {
    return __builtin_amdgcn_mfma_f32_16x16x32_bf16(a, b, c, 0, 0, 0);
}

// packed f32x2 -> bf16x2 (RNE), single instruction
static __device__ inline unsigned int cvtpk(float lo, float hi) {
    unsigned int r;
    asm("v_cvt_pk_bf16_f32 %0, %1, %2" : "=v"(r) : "v"(lo), "v"(hi));
    return r;
}
static __device__ inline float bflo(unsigned int u) { return __builtin_bit_cast(float, u << 16); }
static __device__ inline float bfhi(unsigned int u) { return __builtin_bit_cast(float, u & 0xffff0000u); }

// async global->LDS, 16B per lane. LDS dest must be wave-linear (base + lane*16).
static __device__ inline void gld16(const void* g, void* l) {
    __builtin_amdgcn_global_load_lds(
        (const __attribute__((address_space(1))) unsigned int*)g,
        (__attribute__((address_space(3))) unsigned int*)l, 16, 0, 0);
}

// ---------------------------------------------------------------- LayerNorm
__global__ __launch_bounds__(256) void ln_k(const float* __restrict__ x,
                                            const float* __restrict__ gm,
                                            const float* __restrict__ bt,
                                            bf16* __restrict__ out) {
    int row = blockIdx.x * 4 + (threadIdx.x >> 6);
    int l = threadIdx.x & 63;
    const float* xr = x + (size_t)row * DIMD;
    float v[6];
#pragma unroll
    for (int j = 0; j < 6; ++j) v[j] = xr[l + 64 * j];
    float s = 0.f, s2 = 0.f;
#pragma unroll
    for (int j = 0; j < 6; ++j) { s += v[j]; s2 += v[j] * v[j]; }
#pragma unroll
    for (int m = 1; m < 64; m <<= 1) { s += __shfl_xor(s, m); s2 += __shfl_xor(s2, m); }
    float mu = s * (1.f / DIMD);
    float var = s2 * (1.f / DIMD) - mu * mu;
    float rs = rsqrtf(var + 1e-5f);
    bf16* orow = out + (size_t)row * DIMD;
#pragma unroll
    for (int j = 0; j < 6; ++j) {
        int i = l + 64 * j;
        orow[i] = __float2bfloat16((v[j] - mu) * rs * gm[i] + bt[i]);
    }
}

// ------------------------------------------------- weight transpose + cast
__global__ __launch_bounds__(256) void wtrans_k(const float* __restrict__ W,
                                                bf16* __restrict__ WT,
                                                int K, int N) {
    __shared__ float t[32][33];
    int tx = threadIdx.x & 31, ty = threadIdx.x >> 5;
    int nb = blockIdx.x * 32, kb = blockIdx.y * 32;
#pragma unroll
    for (int i = 0; i < 4; ++i)
        t[ty + 8 * i][tx] = W[(size_t)(kb + ty + 8 * i) * N + nb + tx];
    __syncthreads();
#pragma unroll
    for (int i = 0; i < 4; ++i)
        WT[(size_t)(nb + ty + 8 * i) * K + kb + tx] = __float2bfloat16(t[tx][ty + 8 * i]);
}

// ------------------------------------------------- V transpose (per head)
__global__ __launch_bounds__(256) void vtrans_k(const bf16* __restrict__ v_,
                                                bf16* __restrict__ vT_) {
    const unsigned short* v = (const unsigned short*)v_;
    unsigned short* vT = (unsigned short*)vT_;
    __shared__ unsigned short t[32][33];
    int tx = threadIdx.x & 31, ty = threadIdx.x >> 5;
    int nb = blockIdx.x * 32, db = blockIdx.y * 32;
    int bh = blockIdx.z;
    const unsigned short* src = v + (size_t)bh * SEQ * HD;
#pragma unroll
    for (int i = 0; i < 4; ++i)
        t[ty + 8 * i][tx] = src[(size_t)(nb + ty + 8 * i) * HD + db + tx];
    __syncthreads();
    unsigned short* dst = vT + (size_t)bh * HD * SEQ;
#pragma unroll
    for (int i = 0; i < 4; ++i)
        dst[(size_t)(db + ty + 8 * i) * SEQ + nb + tx] = t[tx][ty + 8 * i];
}

// ------------------------------------------------- dist bias table (permuted)
// DP laid out in exact attn consumption order:
// DP[(b*32+qt)*4+w][t(0..31)][m(0..1)][lane(0..63)] = 16B =
//   {pk(d[k0],d[k0+1]), pk(d[k0+2],d[k0+3]), pk(d[k0+16],d[k0+17]), pk(d[k0+18],d[k0+19])}
// where q = qt*64+w*16+(lane&15), k0 = t*64+32m+4*(lane>>4), d = log2e*exp(-||dpos||^2)
__global__ __launch_bounds__(256) void dist_k(const float* __restrict__ pos,
                                              bf16* __restrict__ DP) {
    int blk = blockIdx.x;                 // (b*32+qt)*4 + w
    int w = blk & 3, qt = (blk >> 2) & 31, b = blk >> 7;
    int l = threadIdx.x & 63, tt = threadIdx.x >> 6;
    int lq = l & 15, g = l >> 4;
    int q = qt * 64 + w * 16 + lq;
    const float* pq = pos + ((size_t)b * SEQ + q) * 3;
    float px = pq[0], py = pq[1], pz = pq[2];
    const float* posb = pos + (size_t)b * SEQ * 3;
    char* base = (char*)DP + (size_t)blk * 65536;
    for (int j = 0; j < 8; ++j) {
        int t = tt * 8 + j;
#pragma unroll
        for (int m = 0; m < 2; ++m) {
            int k0 = t * 64 + 32 * m + 4 * g;
            float a[24];
            const float* pk = posb + 3 * k0;
            *(f32x4*)&a[0]  = *(const f32x4*)pk;
            *(f32x4*)&a[4]  = *(const f32x4*)(pk + 4);
            *(f32x4*)&a[8]  = *(const f32x4*)(pk + 8);
            const float* pk2 = posb + 3 * (k0 + 16);
            *(f32x4*)&a[12] = *(const f32x4*)pk2;
            *(f32x4*)&a[16] = *(const f32x4*)(pk2 + 4);
            *(f32x4*)&a[20] = *(const f32x4*)(pk2 + 8);
            float o8[8];
#pragma unroll
            for (int r = 0; r < 8; ++r) {
                float dx = px - a[3 * r], dy = py - a[3 * r + 1], dz = pz - a[3 * r + 2];
                o8[r] = fexp2(-LOG2E * (dx * dx + dy * dy + dz * dz)) * LOG2E;
            }
            uint4 o;
            o.x = cvtpk(o8[0], o8[1]); o.y = cvtpk(o8[2], o8[3]);
            o.z = cvtpk(o8[4], o8[5]); o.w = cvtpk(o8[6], o8[7]);
            *(uint4*)(base + ((size_t)t * 2 + m) * 1024 + l * 16) = o;
        }
    }
}

// ---------------------------------------------------------------- GEMM
// LDS-staged double-buffered 64x64 tile, BK=64. Source-side XOR chunk swizzle
// (16B chunks within 128B rows), linear LDS dest (global_load_lds constraint).
template <int EPI>
__global__ __launch_bounds__(256) void gemm_k(const bf16* __restrict__ A,
                                              const bf16* __restrict__ WT,
                                              const float* __restrict__ bias,
                                              const float* __restrict__ resid,
                                              float* __restrict__ outf,
                                              bf16* __restrict__ ob0,
                                              bf16* __restrict__ ob1,
                                              bf16* __restrict__ ob2,
                                              int K, int Nw) {
    __shared__ __align__(16) char Als[2][8192];   // [64 m][64 k] bf16
    __shared__ __align__(16) char Bls[2][8192];   // [64 n][64 k] bf16
    int tid = threadIdx.x;
    int w = tid >> 6, l = tid & 63;
    int c = l & 15, g = l >> 4;
    int m0 = blockIdx.y * 64, n0 = blockIdx.x * 64;
    const char* Ag = (const char*)A + (size_t)m0 * K * 2;
    const char* Bg = (const char*)WT + (size_t)n0 * K * 2;
    int K2 = K * 2;

    f32x4 acc[4];
#pragma unroll
    for (int nt = 0; nt < 4; ++nt) acc[nt] = (f32x4){0.f, 0.f, 0.f, 0.f};

    auto stage = [&](int t, int bi) {
#pragma unroll
        for (int p = 0; p < 2; ++p) {
            int chunk = p * 256 + tid;            // 512 x 16B per 8KB buffer
            int r = chunk >> 3;
            int cc = ((chunk & 7) ^ (r & 7)) << 4;
            gld16(Ag + (size_t)r * K2 + t * 128 + cc, &Als[bi][chunk * 16]);
            gld16(Bg + (size_t)r * K2 + t * 128 + cc, &Bls[bi][chunk * 16]);
        }
    };

    stage(0, 0);
    int kcn = K >> 6;
    int arow = (16 * w + c) * 128;
    int sw = c & 7;
    for (int t = 0; t < kcn; ++t) {
        int bi = t & 1;
        __syncthreads();
        if (t + 1 < kcn) stage(t + 1, bi ^ 1);
#pragma unroll
        for (int kk = 0; kk < 2; ++kk) {
            int ch = ((kk * 4 + g) ^ sw) << 4;
            bf16x8 af;
            __builtin_memcpy(&af, &Als[bi][arow + ch], 16);
#pragma unroll
            for (int nt = 0; nt < 4; ++nt) {
                bf16x8 bfr;
                __builtin_memcpy(&bfr, &Bls[bi][(nt * 16 + c) * 128 + ch], 16);
                acc[nt] = mfma16(af, bfr, acc[nt]);
            }
        }
    }

#pragma unroll
    for (int nt = 0; nt < 4; ++nt) {
        int ntb = n0 + nt * 16;
#pragma unroll
        for (int r = 0; r < 4; ++r) {
            int m = m0 + 16 * w + 4 * g + r;
            int n = ntb + c;
            float val = acc[nt][r] + bias[n];
            if (EPI == 0) {
                int which = ntb / DIMD;
                int rem = ntb - which * DIMD;
                int h = rem >> 6;
                int d = (rem & 63) + c;
                int b = m >> 11, s = m & (SEQ - 1);
                bf16* dp = which == 0 ? ob0 : (which == 1 ? ob1 : ob2);
                dp[(((size_t)b * NHEADS + h) * SEQ + s) * HD + d] = __float2bfloat16(val);
            } else if (EPI == 1 || EPI == 3) {
                val += resid[(size_t)m * Nw + n];
                outf[(size_t)m * Nw + n] = val;
            } else {
                float ge = 0.5f * val * (1.0f + erff(val * 0.70710678118654752f));
                ob0[(size_t)m * Nw + n] = __float2bfloat16(ge);
            }
        }
    }
}

// ---------------------------------------------------------------- Attention
// K/V LDS-staged (dbuf, XOR source swizzle); dist bias from permuted DP table
// via coalesced per-lane register loads prefetched one iter ahead.
__global__ __launch_bounds__(256) void attn_k(const bf16* __restrict__ q,
                                              const bf16* __restrict__ k,
                                              const bf16* __restrict__ vT,
                                              const bf16* __restrict__ DP,
                                              bf16* __restrict__ out) {
    __shared__ __align__(16) char Kls[2][8192];   // K  [64 k-rows][64 d]
    __shared__ __align__(16) char Vls[2][8192];   // V^T[64 d-rows][64 k]
    __shared__ __align__(16) unsigned int P_lds[4][16][20];

    int tid = threadIdx.x;
    int w = tid >> 6, l = tid & 63;
    int lq = l & 15, g = l >> 4;
    int qt = blockIdx.x & 31;
    int bh = blockIdx.x >> 5;
    int b = bh / NHEADS, h = bh % NHEADS;
    int qrow = qt * 64 + w * 16 + lq;

    const bf16* qp = q + ((size_t)bh * SEQ + qrow) * HD + 8 * g;
    bf16x8 qf0 = *(const bf16x8*)qp;
    bf16x8 qf1 = *(const bf16x8*)(qp + 32);

    const char* kgb = (const char*)(k + (size_t)bh * SEQ * HD);
    const char* vgb = (const char*)(vT + (size_t)bh * HD * SEQ);
    const char* dpb = (const char*)DP + ((size_t)((b * 32 + qt) * 4 + w)) * 65536 + l * 16;

    const float SC2 = 0.125f * LOG2E;
    float lrun = 0.f;
    f32x4 oacc[4];
#pragma unroll
    for (int dt = 0; dt < 4; ++dt) oacc[dt] = (f32x4){0.f, 0.f, 0.f, 0.f};

    auto stage = [&](int t, int bi) {
#pragma unroll
        for (int p = 0; p < 2; ++p) {
            int chunk = p * 256 + tid;
            int r = chunk >> 3, c = chunk & 7;
            int cc = (c ^ (r & 7)) << 4;
            gld16(kgb + (size_t)t * 8192 + r * 128 + cc, &Kls[bi][chunk * 16]);
            gld16(vgb + (size_t)r * 4096 + t * 128 + cc, &Vls[bi][chunk * 16]);
        }
    };

    stage(0, 0);
    uint4 cdp0 = *(const uint4*)(dpb);
    uint4 cdp1 = *(const uint4*)(dpb + 1024);

    int swq = lq & 7;
    for (int t = 0; t < 32; ++t) {
        int bi = t & 1;
        __syncthreads();
        uint4 ndp0 = {0, 0, 0, 0}, ndp1 = {0, 0, 0, 0};
        if (t + 1 < 32) {
            stage(t + 1, bi ^ 1);
            const char* dpn = dpb + (size_t)(t + 1) * 2048;
            ndp0 = *(const uint4*)(dpn);
            ndp1 = *(const uint4*)(dpn + 1024);
        }

        // QK^T: S^T fragments for 4 k-subtiles of 16
        f32x4 st[4];
#pragma unroll
        for (int s = 0; s < 4; ++s) {
            int ro = (16 * s + lq) * 128;
            bf16x8 klo, khi;
            __builtin_memcpy(&klo, &Kls[bi][ro + ((g ^ swq) << 4)], 16);
            __builtin_memcpy(&khi, &Kls[bi][ro + (((4 + g) ^ swq) << 4)], 16);
            f32x4 z = (f32x4){0.f, 0.f, 0.f, 0.f};
            st[s] = mfma16(klo, qf0, z);
            st[s] = mfma16(khi, qf1, st[s]);
        }

#pragma unroll
        for (int m = 0; m < 2; ++m) {
            uint4 cd = m == 0 ? cdp0 : cdp1;
            f32x4 s0v = st[2 * m], s1v = st[2 * m + 1];
            float p[8];
            p[0] = fexp2(s0v[0] * SC2 + bflo(cd.x));
            p[1] = fexp2(s0v[1] * SC2 + bfhi(cd.x));
            p[2] = fexp2(s0v[2] * SC2 + bflo(cd.y));
            p[3] = fexp2(s0v[3] * SC2 + bfhi(cd.y));
            p[4] = fexp2(s1v[0] * SC2 + bflo(cd.z));
            p[5] = fexp2(s1v[1] * SC2 + bfhi(cd.z));
            p[6] = fexp2(s1v[2] * SC2 + bflo(cd.w));
            p[7] = fexp2(s1v[3] * SC2 + bfhi(cd.w));
            float ps = 0.f;
#pragma unroll
            for (int i = 0; i < 8; ++i) ps += p[i];
            ps += __shfl_xor(ps, 16);
            ps += __shfl_xor(ps, 32);
            lrun += ps;

            P_lds[w][lq][2 * g] = cvtpk(p[0], p[1]);
            P_lds[w][lq][2 * g + 1] = cvtpk(p[2], p[3]);
            P_lds[w][lq][8 + 2 * g] = cvtpk(p[4], p[5]);
            P_lds[w][lq][8 + 2 * g + 1] = cvtpk(p[6], p[7]);
            bf16x8 pf;
            __builtin_memcpy(&pf, &P_lds[w][lq][4 * g], 16);

#pragma unroll
            for (int dt = 0; dt < 4; ++dt) {
                int rv = (16 * dt + lq) * 128;
                bf16x8 vf;
                __builtin_memcpy(&vf, &Vls[bi][rv + (((4 * m + g) ^ swq) << 4)], 16);
                oacc[dt] = mfma16(vf, pf, oacc[dt]);
            }
        }
        cdp0 = ndp0; cdp1 = ndp1;
    }

    float inv = 1.f / lrun;
    bf16* op = out + ((size_t)b * SEQ + qrow) * DIMD + h * HD + 4 * g;
#pragma unroll
    for (int dt = 0; dt < 4; ++dt) {
        unsigned int t2[2];
        t2[0] = cvtpk(oacc[dt][0] * inv, oacc[dt][1] * inv);
        t2[1] = cvtpk(oacc[dt][2] * inv, oacc[dt][3] * inv);
        __builtin_memcpy(op + dt * 16, t2, 8);
    }
}

// ---------------------------------------------------------------- launch
extern "C" void kernel_launch(void* const* d_in, const int* in_sizes, int n_in,
                              void* d_out, int out_size, void* d_ws, size_t ws_size,
                              hipStream_t stream) {
    const float* x      = (const float*)d_in[0];
    const float* pos    = (const float*)d_in[1];
    const float* qkv_w  = (const float*)d_in[2];
    const float* qkv_b  = (const float*)d_in[3];
    const float* proj_w = (const float*)d_in[4];
    const float* proj_b = (const float*)d_in[5];
    const float* mlp_w1 = (const float*)d_in[6];
    const float* mlp_b1 = (const float*)d_in[7];
    const float* mlp_w2 = (const float*)d_in[8];
    const float* mlp_b2 = (const float*)d_in[9];
    const float* ln1_g  = (const float*)d_in[10];
    const float* ln1_b  = (const float*)d_in[11];
    const float* ln2_g  = (const float*)d_in[12];
    const float* ln2_b  = (const float*)d_in[13];

    char* p = (char*)d_ws;
    size_t off = 0;
    auto alloc = [&](size_t bytes) {
        char* r = p + off;
        off = (off + bytes + 255) & ~(size_t)255;
        return r;
    };
    bf16* WT1 = (bf16*)alloc((size_t)1152 * 384 * 2);
    bf16* WT2 = (bf16*)alloc((size_t)384 * 384 * 2);
    bf16* WT3 = (bf16*)alloc((size_t)384 * 768 * 2);
    bf16* WT4 = (bf16*)alloc((size_t)768 * 384 * 2);
    bf16* xn  = (bf16*)alloc((size_t)NTOK * DIMD * 2);
    bf16* xn2 = (bf16*)alloc((size_t)NTOK * DIMD * 2);
    bf16* qb  = (bf16*)alloc((size_t)NTOK * DIMD * 2);
    bf16* kb  = (bf16*)alloc((size_t)NTOK * DIMD * 2);
    bf16* vb  = (bf16*)alloc((size_t)NTOK * DIMD * 2);
    bf16* vTb = (bf16*)alloc((size_t)NTOK * DIMD * 2);
    bf16* ao  = (bf16*)alloc((size_t)NTOK * DIMD * 2);
    float* x1 = (float*)alloc((size_t)NTOK * DIMD * 4);
    bf16* hh  = (bf16*)alloc((size_t)NTOK * MLPH * 2);
    bf16* dtab = (bf16*)alloc((size_t)NBATCH * SEQ * SEQ * 2);  // 32 MiB (DP)
    if (off > ws_size) return;  // workspace too small; cannot run

    wtrans_k<<<dim3(36, 12), 256, 0, stream>>>(qkv_w, WT1, 384, 1152);
    wtrans_k<<<dim3(12, 12), 256, 0, stream>>>(proj_w, WT2, 384, 384);
    wtrans_k<<<dim3(24, 12), 256, 0, stream>>>(mlp_w1, WT3, 384, 768);
    wtrans_k<<<dim3(12, 24), 256, 0, stream>>>(mlp_w2, WT4, 768, 384);

    dist_k<<<NBATCH * 32 * 4, 256, 0, stream>>>(pos, dtab);

    ln_k<<<NTOK / 4, 256, 0, stream>>>(x, ln1_g, ln1_b, xn);
    gemm_k<0><<<dim3(1152 / 64, NTOK / 64), 256, 0, stream>>>(
        xn, WT1, qkv_b, nullptr, nullptr, qb, kb, vb, 384, 1152);
    vtrans_k<<<dim3(SEQ / 32, HD / 32, NBATCH * NHEADS), 256, 0, stream>>>(vb, vTb);
    attn_k<<<NBATCH * NHEADS * (SEQ / 64), 256, 0, stream>>>(qb, kb, vTb, dtab, ao);
    gemm_k<1><<<dim3(384 / 64, NTOK / 64), 256, 0, stream>>>(
        ao, WT2, proj_b, x, x1, nullptr, nullptr, nullptr, 384, 384);
    ln_k<<<NTOK / 4, 256, 0, stream>>>(x1, ln2_g, ln2_b, xn2);
    gemm_k<2><<<dim3(768 / 64, NTOK / 64), 256, 0, stream>>>(
        xn2, WT3, mlp_b1, nullptr, nullptr, hh, nullptr, nullptr, 384, 768);
    gemm_k<3><<<dim3(384 / 64, NTOK / 64), 256, 0, stream>>>(
        hh, WT4, mlp_b2, x1, (float*)d_out, nullptr, nullptr, nullptr, 768, 384);
}

// Round 6
// 152.942 us; speedup vs baseline: 2.6926x; 1.0078x over previous
//
#include <hip/hip_runtime.h>
#include <hip/hip_bf16.h>
#include <math.h>

#define DIMD 384
#define NHEADS 6
#define HD 64
#define MLPH 768
#define SEQ 2048
#define NBATCH 4
#define NTOK (NBATCH*SEQ)   // 8192

typedef __hip_bfloat16 bf16;

typedef __attribute__((ext_vector_type(8))) short bf16x8;
typedef __attribute__((ext_vector_type(4))) float f32x4;

#define LOG2E 1.44269504088896340736f

static __device__ inline float fexp2(float x) { return __builtin_amdgcn_exp2f(x); }

static __device__ inline f32x4 mfma16(bf16x8 a, bf16x8 b, f32x4 c) {
    return __builtin_amdgcn_mfma_f32_16x16x32_bf16(a, b, c, 0, 0, 0);
}

// packed f32x2 -> bf16x2 (RNE), single instruction
static __device__ inline unsigned int cvtpk(float lo, float hi) {
    unsigned int r;
    asm("v_cvt_pk_bf16_f32 %0, %1, %2" : "=v"(r) : "v"(lo), "v"(hi));
    return r;
}
static __device__ inline float bflo(unsigned int u) { return __builtin_bit_cast(float, u << 16); }
static __device__ inline float bfhi(unsigned int u) { return __builtin_bit_cast(float, u & 0xffff0000u); }

// async global->LDS, 16B per lane. LDS dest must be wave-linear (base + lane*16).
static __device__ inline void gld16(const void* g, void* l) {
    __builtin_amdgcn_global_load_lds(
        (const __attribute__((address_space(1))) unsigned int*)g,
        (__attribute__((address_space(3))) unsigned int*)l, 16, 0, 0);
}

// ---------------------------------------------------------------- LayerNorm
__global__ __launch_bounds__(256) void ln_k(const float* __restrict__ x,
                                            const float* __restrict__ gm,
                                            const float* __restrict__ bt,
                                            bf16* __restrict__ out) {
    int row = blockIdx.x * 4 + (threadIdx.x >> 6);
    int l = threadIdx.x & 63;
    const float* xr = x + (size_t)row * DIMD;
    float v[6];
#pragma unroll
    for (int j = 0; j < 6; ++j) v[j] = xr[l + 64 * j];
    float s = 0.f, s2 = 0.f;
#pragma unroll
    for (int j = 0; j < 6; ++j) { s += v[j]; s2 += v[j] * v[j]; }
#pragma unroll
    for (int m = 1; m < 64; m <<= 1) { s += __shfl_xor(s, m); s2 += __shfl_xor(s2, m); }
    float mu = s * (1.f / DIMD);
    float var = s2 * (1.f / DIMD) - mu * mu;
    float rs = rsqrtf(var + 1e-5f);
    bf16* orow = out + (size_t)row * DIMD;
#pragma unroll
    for (int j = 0; j < 6; ++j) {
        int i = l + 64 * j;
        orow[i] = __float2bfloat16((v[j] - mu) * rs * gm[i] + bt[i]);
    }
}

// ------------------------------------------------- weight transpose + cast
__global__ __launch_bounds__(256) void wtrans_k(const float* __restrict__ W,
                                                bf16* __restrict__ WT,
                                                int K, int N) {
    __shared__ float t[32][33];
    int tx = threadIdx.x & 31, ty = threadIdx.x >> 5;
    int nb = blockIdx.x * 32, kb = blockIdx.y * 32;
#pragma unroll
    for (int i = 0; i < 4; ++i)
        t[ty + 8 * i][tx] = W[(size_t)(kb + ty + 8 * i) * N + nb + tx];
    __syncthreads();
#pragma unroll
    for (int i = 0; i < 4; ++i)
        WT[(size_t)(nb + ty + 8 * i) * K + kb + tx] = __float2bfloat16(t[tx][ty + 8 * i]);
}

// ------------------------------------------------- V transpose (per head)
__global__ __launch_bounds__(256) void vtrans_k(const bf16* __restrict__ v_,
                                                bf16* __restrict__ vT_) {
    const unsigned short* v = (const unsigned short*)v_;
    unsigned short* vT = (unsigned short*)vT_;
    __shared__ unsigned short t[32][33];
    int tx = threadIdx.x & 31, ty = threadIdx.x >> 5;
    int nb = blockIdx.x * 32, db = blockIdx.y * 32;
    int bh = blockIdx.z;
    const unsigned short* src = v + (size_t)bh * SEQ * HD;
#pragma unroll
    for (int i = 0; i < 4; ++i)
        t[ty + 8 * i][tx] = src[(size_t)(nb + ty + 8 * i) * HD + db + tx];
    __syncthreads();
    unsigned short* dst = vT + (size_t)bh * HD * SEQ;
#pragma unroll
    for (int i = 0; i < 4; ++i)
        dst[(size_t)(db + ty + 8 * i) * SEQ + nb + tx] = t[tx][ty + 8 * i];
}

// ------------------------------------------------- dist bias table (permuted)
// DP[(b*32+qt)*4+w][t][m][lane] -> 16B in exact attn consumption order
__global__ __launch_bounds__(256) void dist_k(const float* __restrict__ pos,
                                              bf16* __restrict__ DP) {
    int blk = blockIdx.x;                 // (b*32+qt)*4 + w
    int w = blk & 3, qt = (blk >> 2) & 31, b = blk >> 7;
    int l = threadIdx.x & 63, tt = threadIdx.x >> 6;
    int lq = l & 15, g = l >> 4;
    int q = qt * 64 + w * 16 + lq;
    const float* pq = pos + ((size_t)b * SEQ + q) * 3;
    float px = pq[0], py = pq[1], pz = pq[2];
    const float* posb = pos + (size_t)b * SEQ * 3;
    char* base = (char*)DP + (size_t)blk * 65536;
    for (int j = 0; j < 8; ++j) {
        int t = tt * 8 + j;
#pragma unroll
        for (int m = 0; m < 2; ++m) {
            int k0 = t * 64 + 32 * m + 4 * g;
            float a[24];
            const float* pk = posb + 3 * k0;
            *(f32x4*)&a[0]  = *(const f32x4*)pk;
            *(f32x4*)&a[4]  = *(const f32x4*)(pk + 4);
            *(f32x4*)&a[8]  = *(const f32x4*)(pk + 8);
            const float* pk2 = posb + 3 * (k0 + 16);
            *(f32x4*)&a[12] = *(const f32x4*)pk2;
            *(f32x4*)&a[16] = *(const f32x4*)(pk2 + 4);
            *(f32x4*)&a[20] = *(const f32x4*)(pk2 + 8);
            float o8[8];
#pragma unroll
            for (int r = 0; r < 8; ++r) {
                float dx = px - a[3 * r], dy = py - a[3 * r + 1], dz = pz - a[3 * r + 2];
                o8[r] = fexp2(-LOG2E * (dx * dx + dy * dy + dz * dz)) * LOG2E;
            }
            uint4 o;
            o.x = cvtpk(o8[0], o8[1]); o.y = cvtpk(o8[2], o8[3]);
            o.z = cvtpk(o8[4], o8[5]); o.w = cvtpk(o8[6], o8[7]);
            *(uint4*)(base + ((size_t)t * 2 + m) * 1024 + l * 16) = o;
        }
    }
}

// ------------------------------------------- GEMM 128x128 (m97 structure)
// BK=32, 4 waves in 2x2, each wave 64x64 quadrant (4x4 fp32x4 acc).
// 16 MFMA : 8 ds_read_b128 : 4 gld16 per K-step. EPI 0: qkv scatter; 2: gelu.
template <int EPI>
__global__ __launch_bounds__(256) void gemm128_k(const bf16* __restrict__ A,
                                                 const bf16* __restrict__ WT,
                                                 const float* __restrict__ bias,
                                                 bf16* __restrict__ ob0,
                                                 bf16* __restrict__ ob1,
                                                 bf16* __restrict__ ob2,
                                                 int K, int Nw) {
    __shared__ __align__(16) char Als[2][8192];   // [128 m][32 k] bf16
    __shared__ __align__(16) char Bls[2][8192];   // [128 n][32 k] bf16
    int tid = threadIdx.x;
    int w = tid >> 6, l = tid & 63;
    int c = l & 15, g = l >> 4;
    int wr = w >> 1, wc = w & 1;
    int m0 = blockIdx.y * 128, n0 = blockIdx.x * 128;
    const char* Ag = (const char*)A + (size_t)m0 * K * 2;
    const char* Bg = (const char*)WT + (size_t)n0 * K * 2;
    int K2 = K * 2;

    f32x4 acc[4][4];
#pragma unroll
    for (int mi = 0; mi < 4; ++mi)
#pragma unroll
        for (int ni = 0; ni < 4; ++ni) acc[mi][ni] = (f32x4){0.f, 0.f, 0.f, 0.f};

    auto stage = [&](int t, int bi) {
#pragma unroll
        for (int p = 0; p < 2; ++p) {
            int chunk = p * 256 + tid;            // 512 x 16B per 8KB tile
            int r = chunk >> 2;                   // row 0..127 (64B rows)
            int cc = ((chunk & 3) ^ (r & 3)) << 4;
            gld16(Ag + (size_t)r * K2 + t * 64 + cc, &Als[bi][chunk * 16]);
            gld16(Bg + (size_t)r * K2 + t * 64 + cc, &Bls[bi][chunk * 16]);
        }
    };

    stage(0, 0);
    int kcn = K >> 5;
    for (int t = 0; t < kcn; ++t) {
        int bi = t & 1;
        __syncthreads();
        if (t + 1 < kcn) stage(t + 1, bi ^ 1);
        bf16x8 af[4], bfr[4];
#pragma unroll
        for (int mi = 0; mi < 4; ++mi) {
            int row = wr * 64 + mi * 16 + c;
            __builtin_memcpy(&af[mi], &Als[bi][row * 64 + ((g ^ (row & 3)) << 4)], 16);
        }
#pragma unroll
        for (int ni = 0; ni < 4; ++ni) {
            int row = wc * 64 + ni * 16 + c;
            __builtin_memcpy(&bfr[ni], &Bls[bi][row * 64 + ((g ^ (row & 3)) << 4)], 16);
        }
#pragma unroll
        for (int mi = 0; mi < 4; ++mi)
#pragma unroll
            for (int ni = 0; ni < 4; ++ni)
                acc[mi][ni] = mfma16(af[mi], bfr[ni], acc[mi][ni]);
    }

#pragma unroll
    for (int mi = 0; mi < 4; ++mi) {
#pragma unroll
        for (int ni = 0; ni < 4; ++ni) {
            int ntb = n0 + wc * 64 + ni * 16;
#pragma unroll
            for (int r = 0; r < 4; ++r) {
                int m = m0 + wr * 64 + mi * 16 + 4 * g + r;
                int n = ntb + c;
                float val = acc[mi][ni][r] + bias[n];
                if (EPI == 0) {
                    int which = ntb / DIMD;
                    int rem = ntb - which * DIMD;
                    int h = rem >> 6;
                    int d = (rem & 63) + c;
                    int b = m >> 11, s = m & (SEQ - 1);
                    bf16* dp = which == 0 ? ob0 : (which == 1 ? ob1 : ob2);
                    dp[(((size_t)b * NHEADS + h) * SEQ + s) * HD + d] = __float2bfloat16(val);
                } else {  // EPI 2: exact gelu -> bf16
                    float ge = 0.5f * val * (1.0f + erff(val * 0.70710678118654752f));
                    ob0[(size_t)m * Nw + n] = __float2bfloat16(ge);
                }
            }
        }
    }
}

// ---------------------------------------------------------------- GEMM 64x64
// (kept for N=384 outputs: proj / mlp2 — better grid occupancy at small N)
template <int EPI>
__global__ __launch_bounds__(256) void gemm_k(const bf16* __restrict__ A,
                                              const bf16* __restrict__ WT,
                                              const float* __restrict__ bias,
                                              const float* __restrict__ resid,
                                              float* __restrict__ outf,
                                              int K, int Nw) {
    __shared__ __align__(16) char Als[2][8192];   // [64 m][64 k] bf16
    __shared__ __align__(16) char Bls[2][8192];   // [64 n][64 k] bf16
    int tid = threadIdx.x;
    int w = tid >> 6, l = tid & 63;
    int c = l & 15, g = l >> 4;
    int m0 = blockIdx.y * 64, n0 = blockIdx.x * 64;
    const char* Ag = (const char*)A + (size_t)m0 * K * 2;
    const char* Bg = (const char*)WT + (size_t)n0 * K * 2;
    int K2 = K * 2;

    f32x4 acc[4];
#pragma unroll
    for (int nt = 0; nt < 4; ++nt) acc[nt] = (f32x4){0.f, 0.f, 0.f, 0.f};

    auto stage = [&](int t, int bi) {
#pragma unroll
        for (int p = 0; p < 2; ++p) {
            int chunk = p * 256 + tid;            // 512 x 16B per 8KB buffer
            int r = chunk >> 3;
            int cc = ((chunk & 7) ^ (r & 7)) << 4;
            gld16(Ag + (size_t)r * K2 + t * 128 + cc, &Als[bi][chunk * 16]);
            gld16(Bg + (size_t)r * K2 + t * 128 + cc, &Bls[bi][chunk * 16]);
        }
    };

    stage(0, 0);
    int kcn = K >> 6;
    int arow = (16 * w + c) * 128;
    int sw = c & 7;
    for (int t = 0; t < kcn; ++t) {
        int bi = t & 1;
        __syncthreads();
        if (t + 1 < kcn) stage(t + 1, bi ^ 1);
#pragma unroll
        for (int kk = 0; kk < 2; ++kk) {
            int ch = ((kk * 4 + g) ^ sw) << 4;
            bf16x8 af;
            __builtin_memcpy(&af, &Als[bi][arow + ch], 16);
#pragma unroll
            for (int nt = 0; nt < 4; ++nt) {
                bf16x8 bfr;
                __builtin_memcpy(&bfr, &Bls[bi][(nt * 16 + c) * 128 + ch], 16);
                acc[nt] = mfma16(af, bfr, acc[nt]);
            }
        }
    }

#pragma unroll
    for (int nt = 0; nt < 4; ++nt) {
        int ntb = n0 + nt * 16;
#pragma unroll
        for (int r = 0; r < 4; ++r) {
            int m = m0 + 16 * w + 4 * g + r;
            int n = ntb + c;
            float val = acc[nt][r] + bias[n];
            val += resid[(size_t)m * Nw + n];
            outf[(size_t)m * Nw + n] = val;
        }
    }
}

// ---------------------------------------------------------------- Attention
__global__ __launch_bounds__(256) void attn_k(const bf16* __restrict__ q,
                                              const bf16* __restrict__ k,
                                              const bf16* __restrict__ vT,
                                              const bf16* __restrict__ DP,
                                              bf16* __restrict__ out) {
    __shared__ __align__(16) char Kls[2][8192];   // K  [64 k-rows][64 d]
    __shared__ __align__(16) char Vls[2][8192];   // V^T[64 d-rows][64 k]
    __shared__ __align__(16) unsigned int P_lds[4][16][20];

    int tid = threadIdx.x;
    int w = tid >> 6, l = tid & 63;
    int lq = l & 15, g = l >> 4;
    int qt = blockIdx.x & 31;
    int bh = blockIdx.x >> 5;
    int b = bh / NHEADS, h = bh % NHEADS;
    int qrow = qt * 64 + w * 16 + lq;

    const bf16* qp = q + ((size_t)bh * SEQ + qrow) * HD + 8 * g;
    bf16x8 qf0 = *(const bf16x8*)qp;
    bf16x8 qf1 = *(const bf16x8*)(qp + 32);

    const char* kgb = (const char*)(k + (size_t)bh * SEQ * HD);
    const char* vgb = (const char*)(vT + (size_t)bh * HD * SEQ);
    const char* dpb = (const char*)DP + ((size_t)((b * 32 + qt) * 4 + w)) * 65536 + l * 16;

    const float SC2 = 0.125f * LOG2E;
    float lloc = 0.f;                 // per-lane partial; cross-lane reduce ONCE at end
    f32x4 oacc[4];
#pragma unroll
    for (int dt = 0; dt < 4; ++dt) oacc[dt] = (f32x4){0.f, 0.f, 0.f, 0.f};

    auto stage = [&](int t, int bi) {
#pragma unroll
        for (int p = 0; p < 2; ++p) {
            int chunk = p * 256 + tid;
            int r = chunk >> 3, c = chunk & 7;
            int cc = (c ^ (r & 7)) << 4;
            gld16(kgb + (size_t)t * 8192 + r * 128 + cc, &Kls[bi][chunk * 16]);
            gld16(vgb + (size_t)r * 4096 + t * 128 + cc, &Vls[bi][chunk * 16]);
        }
    };

    stage(0, 0);
    uint4 cdp0 = *(const uint4*)(dpb);
    uint4 cdp1 = *(const uint4*)(dpb + 1024);

    int swq = lq & 7;
    for (int t = 0; t < 32; ++t) {
        int bi = t & 1;
        __syncthreads();
        uint4 ndp0 = {0, 0, 0, 0}, ndp1 = {0, 0, 0, 0};
        if (t + 1 < 32) {
            stage(t + 1, bi ^ 1);
            const char* dpn = dpb + (size_t)(t + 1) * 2048;
            ndp0 = *(const uint4*)(dpn);
            ndp1 = *(const uint4*)(dpn + 1024);
        }

        f32x4 st[4];
#pragma unroll
        for (int s = 0; s < 4; ++s) {
            int ro = (16 * s + lq) * 128;
            bf16x8 klo, khi;
            __builtin_memcpy(&klo, &Kls[bi][ro + ((g ^ swq) << 4)], 16);
            __builtin_memcpy(&khi, &Kls[bi][ro + (((4 + g) ^ swq) << 4)], 16);
            f32x4 z = (f32x4){0.f, 0.f, 0.f, 0.f};
            st[s] = mfma16(klo, qf0, z);
            st[s] = mfma16(khi, qf1, st[s]);
        }

#pragma unroll
        for (int m = 0; m < 2; ++m) {
            uint4 cd = m == 0 ? cdp0 : cdp1;
            f32x4 s0v = st[2 * m], s1v = st[2 * m + 1];
            float p[8];
            p[0] = fexp2(s0v[0] * SC2 + bflo(cd.x));
            p[1] = fexp2(s0v[1] * SC2 + bfhi(cd.x));
            p[2] = fexp2(s0v[2] * SC2 + bflo(cd.y));
            p[3] = fexp2(s0v[3] * SC2 + bfhi(cd.y));
            p[4] = fexp2(s1v[0] * SC2 + bflo(cd.z));
            p[5] = fexp2(s1v[1] * SC2 + bfhi(cd.z));
            p[6] = fexp2(s1v[2] * SC2 + bflo(cd.w));
            p[7] = fexp2(s1v[3] * SC2 + bfhi(cd.w));
#pragma unroll
            for (int i = 0; i < 8; ++i) lloc += p[i];

            P_lds[w][lq][2 * g] = cvtpk(p[0], p[1]);
            P_lds[w][lq][2 * g + 1] = cvtpk(p[2], p[3]);
            P_lds[w][lq][8 + 2 * g] = cvtpk(p[4], p[5]);
            P_lds[w][lq][8 + 2 * g + 1] = cvtpk(p[6], p[7]);
            bf16x8 pf;
            __builtin_memcpy(&pf, &P_lds[w][lq][4 * g], 16);

#pragma unroll
            for (int dt = 0; dt < 4; ++dt) {
                int rv = (16 * dt + lq) * 128;
                bf16x8 vf;
                __builtin_memcpy(&vf, &Vls[bi][rv + (((4 * m + g) ^ swq) << 4)], 16);
                oacc[dt] = mfma16(vf, pf, oacc[dt]);
            }
        }
        cdp0 = ndp0; cdp1 = ndp1;
    }

    float lrun = lloc;
    lrun += __shfl_xor(lrun, 16);
    lrun += __shfl_xor(lrun, 32);
    float inv = 1.f / lrun;
    bf16* op = out + ((size_t)b * SEQ + qrow) * DIMD + h * HD + 4 * g;
#pragma unroll
    for (int dt = 0; dt < 4; ++dt) {
        unsigned int t2[2];
        t2[0] = cvtpk(oacc[dt][0] * inv, oacc[dt][1] * inv);
        t2[1] = cvtpk(oacc[dt][2] * inv, oacc[dt][3] * inv);
        __builtin_memcpy(op + dt * 16, t2, 8);
    }
}

// ---------------------------------------------------------------- launch
extern "C" void kernel_launch(void* const* d_in, const int* in_sizes, int n_in,
                              void* d_out, int out_size, void* d_ws, size_t ws_size,
                              hipStream_t stream) {
    const float* x      = (const float*)d_in[0];
    const float* pos    = (const float*)d_in[1];
    const float* qkv_w  = (const float*)d_in[2];
    const float* qkv_b  = (const float*)d_in[3];
    const float* proj_w = (const float*)d_in[4];
    const float* proj_b = (const float*)d_in[5];
    const float* mlp_w1 = (const float*)d_in[6];
    const float* mlp_b1 = (const float*)d_in[7];
    const float* mlp_w2 = (const float*)d_in[8];
    const float* mlp_b2 = (const float*)d_in[9];
    const float* ln1_g  = (const float*)d_in[10];
    const float* ln1_b  = (const float*)d_in[11];
    const float* ln2_g  = (const float*)d_in[12];
    const float* ln2_b  = (const float*)d_in[13];

    char* p = (char*)d_ws;
    size_t off = 0;
    auto alloc = [&](size_t bytes) {
        char* r = p + off;
        off = (off + bytes + 255) & ~(size_t)255;
        return r;
    };
    bf16* WT1 = (bf16*)alloc((size_t)1152 * 384 * 2);
    bf16* WT2 = (bf16*)alloc((size_t)384 * 384 * 2);
    bf16* WT3 = (bf16*)alloc((size_t)384 * 768 * 2);
    bf16* WT4 = (bf16*)alloc((size_t)768 * 384 * 2);
    bf16* xn  = (bf16*)alloc((size_t)NTOK * DIMD * 2);
    bf16* xn2 = (bf16*)alloc((size_t)NTOK * DIMD * 2);
    bf16* qb  = (bf16*)alloc((size_t)NTOK * DIMD * 2);
    bf16* kb  = (bf16*)alloc((size_t)NTOK * DIMD * 2);
    bf16* vb  = (bf16*)alloc((size_t)NTOK * DIMD * 2);
    bf16* vTb = (bf16*)alloc((size_t)NTOK * DIMD * 2);
    bf16* ao  = (bf16*)alloc((size_t)NTOK * DIMD * 2);
    float* x1 = (float*)alloc((size_t)NTOK * DIMD * 4);
    bf16* hh  = (bf16*)alloc((size_t)NTOK * MLPH * 2);
    bf16* dtab = (bf16*)alloc((size_t)NBATCH * SEQ * SEQ * 2);  // 32 MiB (DP)
    if (off > ws_size) return;  // workspace too small; cannot run

    wtrans_k<<<dim3(36, 12), 256, 0, stream>>>(qkv_w, WT1, 384, 1152);
    wtrans_k<<<dim3(12, 12), 256, 0, stream>>>(proj_w, WT2, 384, 384);
    wtrans_k<<<dim3(24, 12), 256, 0, stream>>>(mlp_w1, WT3, 384, 768);
    wtrans_k<<<dim3(12, 24), 256, 0, stream>>>(mlp_w2, WT4, 768, 384);

    dist_k<<<NBATCH * 32 * 4, 256, 0, stream>>>(pos, dtab);

    ln_k<<<NTOK / 4, 256, 0, stream>>>(x, ln1_g, ln1_b, xn);
    gemm128_k<0><<<dim3(1152 / 128, NTOK / 128), 256, 0, stream>>>(
        xn, WT1, qkv_b, qb, kb, vb, 384, 1152);
    vtrans_k<<<dim3(SEQ / 32, HD / 32, NBATCH * NHEADS), 256, 0, stream>>>(vb, vTb);
    attn_k<<<NBATCH * NHEADS * (SEQ / 64), 256, 0, stream>>>(qb, kb, vTb, dtab, ao);
    gemm_k<1><<<dim3(384 / 64, NTOK / 64), 256, 0, stream>>>(
        ao, WT2, proj_b, x, x1, 384, 384);
    ln_k<<<NTOK / 4, 256, 0, stream>>>(x1, ln2_g, ln2_b, xn2);
    gemm128_k<2><<<dim3(768 / 128, NTOK / 128), 256, 0, stream>>>(
        xn2, WT3, mlp_b1, hh, nullptr, nullptr, 384, 768);
    gemm_k<3><<<dim3(384 / 64, NTOK / 64), 256, 0, stream>>>(
        hh, WT4, mlp_b2, x1, (float*)d_out, 768, 384);
}

// Round 7
// 144.272 us; speedup vs baseline: 2.8544x; 1.0601x over previous
//
#include <hip/hip_runtime.h>
#include <hip/hip_bf16.h>
#include <math.h>

#define DIMD 384
#define NHEADS 6
#define HD 64
#define MLPH 768
#define SEQ 2048
#define NBATCH 4
#define NTOK (NBATCH*SEQ)   // 8192

typedef __hip_bfloat16 bf16;

typedef __attribute__((ext_vector_type(8))) short bf16x8;
typedef __attribute__((ext_vector_type(4))) float f32x4;

#define LOG2E 1.44269504088896340736f

static __device__ inline float fexp2(float x) { return __builtin_amdgcn_exp2f(x); }

static __device__ inline f32x4 mfma16(bf16x8 a, bf16x8 b, f32x4 c) {
    return __builtin_amdgcn_mfma_f32_16x16x32_bf16(a, b, c, 0, 0, 0);
}

// packed f32x2 -> bf16x2 (RNE), single instruction
static __device__ inline unsigned int cvtpk(float lo, float hi) {
    unsigned int r;
    asm("v_cvt_pk_bf16_f32 %0, %1, %2" : "=v"(r) : "v"(lo), "v"(hi));
    return r;
}
static __device__ inline float bflo(unsigned int u) { return __builtin_bit_cast(float, u << 16); }
static __device__ inline float bfhi(unsigned int u) { return __builtin_bit_cast(float, u & 0xffff0000u); }

// async global->LDS, 16B per lane. LDS dest must be wave-linear (base + lane*16).
static __device__ inline void gld16(const void* g, void* l) {
    __builtin_amdgcn_global_load_lds(
        (const __attribute__((address_space(1))) unsigned int*)g,
        (__attribute__((address_space(3))) unsigned int*)l, 16, 0, 0);
}

// ---------------------------------------------------------------- LayerNorm
__global__ __launch_bounds__(256) void ln_k(const float* __restrict__ x,
                                            const float* __restrict__ gm,
                                            const float* __restrict__ bt,
                                            bf16* __restrict__ out) {
    int row = blockIdx.x * 4 + (threadIdx.x >> 6);
    int l = threadIdx.x & 63;
    const float* xr = x + (size_t)row * DIMD;
    float v[6];
#pragma unroll
    for (int j = 0; j < 6; ++j) v[j] = xr[l + 64 * j];
    float s = 0.f, s2 = 0.f;
#pragma unroll
    for (int j = 0; j < 6; ++j) { s += v[j]; s2 += v[j] * v[j]; }
#pragma unroll
    for (int m = 1; m < 64; m <<= 1) { s += __shfl_xor(s, m); s2 += __shfl_xor(s2, m); }
    float mu = s * (1.f / DIMD);
    float var = s2 * (1.f / DIMD) - mu * mu;
    float rs = rsqrtf(var + 1e-5f);
    bf16* orow = out + (size_t)row * DIMD;
#pragma unroll
    for (int j = 0; j < 6; ++j) {
        int i = l + 64 * j;
        orow[i] = __float2bfloat16((v[j] - mu) * rs * gm[i] + bt[i]);
    }
}

// ------------------------------------- all weight transposes, one launch
// W [K][N] f32 -> WT [N][K] bf16, four weight matrices by linear block id
__global__ __launch_bounds__(256) void wtransall_k(const float* __restrict__ w1,
                                                   const float* __restrict__ w2,
                                                   const float* __restrict__ w3,
                                                   const float* __restrict__ w4,
                                                   bf16* __restrict__ o1,
                                                   bf16* __restrict__ o2,
                                                   bf16* __restrict__ o3,
                                                   bf16* __restrict__ o4) {
    __shared__ float t[32][33];
    int id = blockIdx.x;
    const float* W; bf16* O; int K, N;
    if (id < 432)      { W = w1; O = o1; K = 384; N = 1152; }
    else if (id < 576) { W = w2; O = o2; K = 384; N = 384;  id -= 432; }
    else if (id < 864) { W = w3; O = o3; K = 384; N = 768;  id -= 576; }
    else               { W = w4; O = o4; K = 768; N = 384;  id -= 864; }
    int nbx = N >> 5;
    int nb = (id % nbx) * 32, kb = (id / nbx) * 32;
    int tx = threadIdx.x & 31, ty = threadIdx.x >> 5;
#pragma unroll
    for (int i = 0; i < 4; ++i)
        t[ty + 8 * i][tx] = W[(size_t)(kb + ty + 8 * i) * N + nb + tx];
    __syncthreads();
#pragma unroll
    for (int i = 0; i < 4; ++i)
        O[(size_t)(nb + ty + 8 * i) * K + kb + tx] = __float2bfloat16(t[tx][ty + 8 * i]);
}

// ------------------------------------------------- V transpose (per head)
// v [BH][SEQ][HD] -> vT [BH][HD][SEQ] with PV-permuted columns:
// within each 32-key group, col slot kappa holds physical key pi(kappa),
// pi(8g+j) = 4g+j (j<4), 16+4g+(j-4) (j>=4). Equivalently store key r at
// slot invp(r) = 8*((r&15)>>2) + 4*(r>>4) + (r&3). This makes QK's C-layout
// directly PV-consumable (no P repack through LDS in attn_k).
__global__ __launch_bounds__(256) void vtrans_k(const bf16* __restrict__ v_,
                                                bf16* __restrict__ vT_) {
    const unsigned short* v = (const unsigned short*)v_;
    unsigned short* vT = (unsigned short*)vT_;
    __shared__ unsigned short t[32][33];
    int tx = threadIdx.x & 31, ty = threadIdx.x >> 5;
    int nb = blockIdx.x * 32, db = blockIdx.y * 32;
    int bh = blockIdx.z;
    const unsigned short* src = v + (size_t)bh * SEQ * HD;
#pragma unroll
    for (int i = 0; i < 4; ++i)
        t[ty + 8 * i][tx] = src[(size_t)(nb + ty + 8 * i) * HD + db + tx];
    __syncthreads();
    unsigned short* dst = vT + (size_t)bh * HD * SEQ;
    int pc = 8 * ((tx & 15) >> 2) + 4 * (tx >> 4) + (tx & 3);   // invp
#pragma unroll
    for (int i = 0; i < 4; ++i)
        dst[(size_t)(db + ty + 8 * i) * SEQ + nb + pc] = t[tx][ty + 8 * i];
}

// ------------------------------------------------- dist bias table (permuted)
// DP[(b*32+qt)*4+w][t][m][lane] -> 16B in exact attn consumption order
__global__ __launch_bounds__(256) void dist_k(const float* __restrict__ pos,
                                              bf16* __restrict__ DP) {
    int blk = blockIdx.x;                 // (b*32+qt)*4 + w
    int w = blk & 3, qt = (blk >> 2) & 31, b = blk >> 7;
    int l = threadIdx.x & 63, tt = threadIdx.x >> 6;
    int lq = l & 15, g = l >> 4;
    int q = qt * 64 + w * 16 + lq;
    const float* pq = pos + ((size_t)b * SEQ + q) * 3;
    float px = pq[0], py = pq[1], pz = pq[2];
    const float* posb = pos + (size_t)b * SEQ * 3;
    char* base = (char*)DP + (size_t)blk * 65536;
    for (int j = 0; j < 8; ++j) {
        int t = tt * 8 + j;
#pragma unroll
        for (int m = 0; m < 2; ++m) {
            int k0 = t * 64 + 32 * m + 4 * g;
            float a[24];
            const float* pk = posb + 3 * k0;
            *(f32x4*)&a[0]  = *(const f32x4*)pk;
            *(f32x4*)&a[4]  = *(const f32x4*)(pk + 4);
            *(f32x4*)&a[8]  = *(const f32x4*)(pk + 8);
            const float* pk2 = posb + 3 * (k0 + 16);
            *(f32x4*)&a[12] = *(const f32x4*)pk2;
            *(f32x4*)&a[16] = *(const f32x4*)(pk2 + 4);
            *(f32x4*)&a[20] = *(const f32x4*)(pk2 + 8);
            float o8[8];
#pragma unroll
            for (int r = 0; r < 8; ++r) {
                float dx = px - a[3 * r], dy = py - a[3 * r + 1], dz = pz - a[3 * r + 2];
                o8[r] = fexp2(-LOG2E * (dx * dx + dy * dy + dz * dz)) * LOG2E;
            }
            uint4 o;
            o.x = cvtpk(o8[0], o8[1]); o.y = cvtpk(o8[2], o8[3]);
            o.z = cvtpk(o8[4], o8[5]); o.w = cvtpk(o8[6], o8[7]);
            *(uint4*)(base + ((size_t)t * 2 + m) * 1024 + l * 16) = o;
        }
    }
}

// ------------------------------------------- GEMM 128x128 (m97 structure)
template <int EPI>
__global__ __launch_bounds__(256) void gemm128_k(const bf16* __restrict__ A,
                                                 const bf16* __restrict__ WT,
                                                 const float* __restrict__ bias,
                                                 bf16* __restrict__ ob0,
                                                 bf16* __restrict__ ob1,
                                                 bf16* __restrict__ ob2,
                                                 int K, int Nw) {
    __shared__ __align__(16) char Als[2][8192];   // [128 m][32 k] bf16
    __shared__ __align__(16) char Bls[2][8192];   // [128 n][32 k] bf16
    int tid = threadIdx.x;
    int w = tid >> 6, l = tid & 63;
    int c = l & 15, g = l >> 4;
    int wr = w >> 1, wc = w & 1;
    int m0 = blockIdx.y * 128, n0 = blockIdx.x * 128;
    const char* Ag = (const char*)A + (size_t)m0 * K * 2;
    const char* Bg = (const char*)WT + (size_t)n0 * K * 2;
    int K2 = K * 2;

    f32x4 acc[4][4];
#pragma unroll
    for (int mi = 0; mi < 4; ++mi)
#pragma unroll
        for (int ni = 0; ni < 4; ++ni) acc[mi][ni] = (f32x4){0.f, 0.f, 0.f, 0.f};

    auto stage = [&](int t, int bi) {
#pragma unroll
        for (int p = 0; p < 2; ++p) {
            int chunk = p * 256 + tid;            // 512 x 16B per 8KB tile
            int r = chunk >> 2;                   // row 0..127 (64B rows)
            int cc = ((chunk & 3) ^ (r & 3)) << 4;
            gld16(Ag + (size_t)r * K2 + t * 64 + cc, &Als[bi][chunk * 16]);
            gld16(Bg + (size_t)r * K2 + t * 64 + cc, &Bls[bi][chunk * 16]);
        }
    };

    stage(0, 0);
    int kcn = K >> 5;
    for (int t = 0; t < kcn; ++t) {
        int bi = t & 1;
        __syncthreads();
        if (t + 1 < kcn) stage(t + 1, bi ^ 1);
        bf16x8 af[4], bfr[4];
#pragma unroll
        for (int mi = 0; mi < 4; ++mi) {
            int row = wr * 64 + mi * 16 + c;
            __builtin_memcpy(&af[mi], &Als[bi][row * 64 + ((g ^ (row & 3)) << 4)], 16);
        }
#pragma unroll
        for (int ni = 0; ni < 4; ++ni) {
            int row = wc * 64 + ni * 16 + c;
            __builtin_memcpy(&bfr[ni], &Bls[bi][row * 64 + ((g ^ (row & 3)) << 4)], 16);
        }
#pragma unroll
        for (int mi = 0; mi < 4; ++mi)
#pragma unroll
            for (int ni = 0; ni < 4; ++ni)
                acc[mi][ni] = mfma16(af[mi], bfr[ni], acc[mi][ni]);
    }

#pragma unroll
    for (int mi = 0; mi < 4; ++mi) {
#pragma unroll
        for (int ni = 0; ni < 4; ++ni) {
            int ntb = n0 + wc * 64 + ni * 16;
#pragma unroll
            for (int r = 0; r < 4; ++r) {
                int m = m0 + wr * 64 + mi * 16 + 4 * g + r;
                int n = ntb + c;
                float val = acc[mi][ni][r] + bias[n];
                if (EPI == 0) {
                    int which = ntb / DIMD;
                    int rem = ntb - which * DIMD;
                    int h = rem >> 6;
                    int d = (rem & 63) + c;
                    int b = m >> 11, s = m & (SEQ - 1);
                    bf16* dp = which == 0 ? ob0 : (which == 1 ? ob1 : ob2);
                    dp[(((size_t)b * NHEADS + h) * SEQ + s) * HD + d] = __float2bfloat16(val);
                } else {  // EPI 2: exact gelu -> bf16
                    float ge = 0.5f * val * (1.0f + erff(val * 0.70710678118654752f));
                    ob0[(size_t)m * Nw + n] = __float2bfloat16(ge);
                }
            }
        }
    }
}

// ---------------------------------------------------------------- GEMM 64x64
template <int EPI>
__global__ __launch_bounds__(256) void gemm_k(const bf16* __restrict__ A,
                                              const bf16* __restrict__ WT,
                                              const float* __restrict__ bias,
                                              const float* __restrict__ resid,
                                              float* __restrict__ outf,
                                              int K, int Nw) {
    __shared__ __align__(16) char Als[2][8192];   // [64 m][64 k] bf16
    __shared__ __align__(16) char Bls[2][8192];   // [64 n][64 k] bf16
    int tid = threadIdx.x;
    int w = tid >> 6, l = tid & 63;
    int c = l & 15, g = l >> 4;
    int m0 = blockIdx.y * 64, n0 = blockIdx.x * 64;
    const char* Ag = (const char*)A + (size_t)m0 * K * 2;
    const char* Bg = (const char*)WT + (size_t)n0 * K * 2;
    int K2 = K * 2;

    f32x4 acc[4];
#pragma unroll
    for (int nt = 0; nt < 4; ++nt) acc[nt] = (f32x4){0.f, 0.f, 0.f, 0.f};

    auto stage = [&](int t, int bi) {
#pragma unroll
        for (int p = 0; p < 2; ++p) {
            int chunk = p * 256 + tid;            // 512 x 16B per 8KB buffer
            int r = chunk >> 3;
            int cc = ((chunk & 7) ^ (r & 7)) << 4;
            gld16(Ag + (size_t)r * K2 + t * 128 + cc, &Als[bi][chunk * 16]);
            gld16(Bg + (size_t)r * K2 + t * 128 + cc, &Bls[bi][chunk * 16]);
        }
    };

    stage(0, 0);
    int kcn = K >> 6;
    int arow = (16 * w + c) * 128;
    int sw = c & 7;
    for (int t = 0; t < kcn; ++t) {
        int bi = t & 1;
        __syncthreads();
        if (t + 1 < kcn) stage(t + 1, bi ^ 1);
#pragma unroll
        for (int kk = 0; kk < 2; ++kk) {
            int ch = ((kk * 4 + g) ^ sw) << 4;
            bf16x8 af;
            __builtin_memcpy(&af, &Als[bi][arow + ch], 16);
#pragma unroll
            for (int nt = 0; nt < 4; ++nt) {
                bf16x8 bfr;
                __builtin_memcpy(&bfr, &Bls[bi][(nt * 16 + c) * 128 + ch], 16);
                acc[nt] = mfma16(af, bfr, acc[nt]);
            }
        }
    }

#pragma unroll
    for (int nt = 0; nt < 4; ++nt) {
        int ntb = n0 + nt * 16;
#pragma unroll
        for (int r = 0; r < 4; ++r) {
            int m = m0 + 16 * w + 4 * g + r;
            int n = ntb + c;
            float val = acc[nt][r] + bias[n];
            val += resid[(size_t)m * Nw + n];
            outf[(size_t)m * Nw + n] = val;
        }
    }
}

// ---------------------------------------------------------------- Attention
// K/V LDS-staged (dbuf, XOR source swizzle). V^T columns are pre-permuted so
// the QK C-layout IS the PV B-fragment: pf = 4x cvt_pk of own p[] (no LDS).
__global__ __launch_bounds__(256) void attn_k(const bf16* __restrict__ q,
                                              const bf16* __restrict__ k,
                                              const bf16* __restrict__ vT,
                                              const bf16* __restrict__ DP,
                                              bf16* __restrict__ out) {
    __shared__ __align__(16) char Kls[2][8192];   // K  [64 k-rows][64 d]
    __shared__ __align__(16) char Vls[2][8192];   // V^T[64 d-rows][64 k] (permuted cols)

    int tid = threadIdx.x;
    int w = tid >> 6, l = tid & 63;
    int lq = l & 15, g = l >> 4;
    int qt = blockIdx.x & 31;
    int bh = blockIdx.x >> 5;
    int b = bh / NHEADS, h = bh % NHEADS;
    int qrow = qt * 64 + w * 16 + lq;

    const bf16* qp = q + ((size_t)bh * SEQ + qrow) * HD + 8 * g;
    bf16x8 qf0 = *(const bf16x8*)qp;
    bf16x8 qf1 = *(const bf16x8*)(qp + 32);

    const char* kgb = (const char*)(k + (size_t)bh * SEQ * HD);
    const char* vgb = (const char*)(vT + (size_t)bh * HD * SEQ);
    const char* dpb = (const char*)DP + ((size_t)((b * 32 + qt) * 4 + w)) * 65536 + l * 16;

    const float SC2 = 0.125f * LOG2E;
    float lloc = 0.f;
    f32x4 oacc[4];
#pragma unroll
    for (int dt = 0; dt < 4; ++dt) oacc[dt] = (f32x4){0.f, 0.f, 0.f, 0.f};

    auto stage = [&](int t, int bi) {
#pragma unroll
        for (int p = 0; p < 2; ++p) {
            int chunk = p * 256 + tid;
            int r = chunk >> 3, c = chunk & 7;
            int cc = (c ^ (r & 7)) << 4;
            gld16(kgb + (size_t)t * 8192 + r * 128 + cc, &Kls[bi][chunk * 16]);
            gld16(vgb + (size_t)r * 4096 + t * 128 + cc, &Vls[bi][chunk * 16]);
        }
    };

    stage(0, 0);
    uint4 cdp0 = *(const uint4*)(dpb);
    uint4 cdp1 = *(const uint4*)(dpb + 1024);

    int swq = lq & 7;
    for (int t = 0; t < 32; ++t) {
        int bi = t & 1;
        __syncthreads();
        uint4 ndp0 = {0, 0, 0, 0}, ndp1 = {0, 0, 0, 0};
        if (t + 1 < 32) {
            stage(t + 1, bi ^ 1);
            const char* dpn = dpb + (size_t)(t + 1) * 2048;
            ndp0 = *(const uint4*)(dpn);
            ndp1 = *(const uint4*)(dpn + 1024);
        }

        f32x4 st[4];
#pragma unroll
        for (int s = 0; s < 4; ++s) {
            int ro = (16 * s + lq) * 128;
            bf16x8 klo, khi;
            __builtin_memcpy(&klo, &Kls[bi][ro + ((g ^ swq) << 4)], 16);
            __builtin_memcpy(&khi, &Kls[bi][ro + (((4 + g) ^ swq) << 4)], 16);
            f32x4 z = (f32x4){0.f, 0.f, 0.f, 0.f};
            st[s] = mfma16(klo, qf0, z);
            st[s] = mfma16(khi, qf1, st[s]);
        }

#pragma unroll
        for (int m = 0; m < 2; ++m) {
            uint4 cd = m == 0 ? cdp0 : cdp1;
            f32x4 s0v = st[2 * m], s1v = st[2 * m + 1];
            float p[8];
            p[0] = fexp2(s0v[0] * SC2 + bflo(cd.x));
            p[1] = fexp2(s0v[1] * SC2 + bfhi(cd.x));
            p[2] = fexp2(s0v[2] * SC2 + bflo(cd.y));
            p[3] = fexp2(s0v[3] * SC2 + bfhi(cd.y));
            p[4] = fexp2(s1v[0] * SC2 + bflo(cd.z));
            p[5] = fexp2(s1v[1] * SC2 + bfhi(cd.z));
            p[6] = fexp2(s1v[2] * SC2 + bflo(cd.w));
            p[7] = fexp2(s1v[3] * SC2 + bfhi(cd.w));
#pragma unroll
            for (int i = 0; i < 8; ++i) lloc += p[i];

            unsigned int pw[4];
            pw[0] = cvtpk(p[0], p[1]);
            pw[1] = cvtpk(p[2], p[3]);
            pw[2] = cvtpk(p[4], p[5]);
            pw[3] = cvtpk(p[6], p[7]);
            bf16x8 pf;
            __builtin_memcpy(&pf, pw, 16);

#pragma unroll
            for (int dt = 0; dt < 4; ++dt) {
                int rv = (16 * dt + lq) * 128;
                bf16x8 vf;
                __builtin_memcpy(&vf, &Vls[bi][rv + (((4 * m + g) ^ swq) << 4)], 16);
                oacc[dt] = mfma16(vf, pf, oacc[dt]);
            }
        }
        cdp0 = ndp0; cdp1 = ndp1;
    }

    float lrun = lloc;
    lrun += __shfl_xor(lrun, 16);
    lrun += __shfl_xor(lrun, 32);
    float inv = 1.f / lrun;
    bf16* op = out + ((size_t)b * SEQ + qrow) * DIMD + h * HD + 4 * g;
#pragma unroll
    for (int dt = 0; dt < 4; ++dt) {
        unsigned int t2[2];
        t2[0] = cvtpk(oacc[dt][0] * inv, oacc[dt][1] * inv);
        t2[1] = cvtpk(oacc[dt][2] * inv, oacc[dt][3] * inv);
        __builtin_memcpy(op + dt * 16, t2, 8);
    }
}

// ---------------------------------------------------------------- launch
extern "C" void kernel_launch(void* const* d_in, const int* in_sizes, int n_in,
                              void* d_out, int out_size, void* d_ws, size_t ws_size,
                              hipStream_t stream) {
    const float* x      = (const float*)d_in[0];
    const float* pos    = (const float*)d_in[1];
    const float* qkv_w  = (const float*)d_in[2];
    const float* qkv_b  = (const float*)d_in[3];
    const float* proj_w = (const float*)d_in[4];
    const float* proj_b = (const float*)d_in[5];
    const float* mlp_w1 = (const float*)d_in[6];
    const float* mlp_b1 = (const float*)d_in[7];
    const float* mlp_w2 = (const float*)d_in[8];
    const float* mlp_b2 = (const float*)d_in[9];
    const float* ln1_g  = (const float*)d_in[10];
    const float* ln1_b  = (const float*)d_in[11];
    const float* ln2_g  = (const float*)d_in[12];
    const float* ln2_b  = (const float*)d_in[13];

    char* p = (char*)d_ws;
    size_t off = 0;
    auto alloc = [&](size_t bytes) {
        char* r = p + off;
        off = (off + bytes + 255) & ~(size_t)255;
        return r;
    };
    bf16* WT1 = (bf16*)alloc((size_t)1152 * 384 * 2);
    bf16* WT2 = (bf16*)alloc((size_t)384 * 384 * 2);
    bf16* WT3 = (bf16*)alloc((size_t)384 * 768 * 2);
    bf16* WT4 = (bf16*)alloc((size_t)768 * 384 * 2);
    bf16* xn  = (bf16*)alloc((size_t)NTOK * DIMD * 2);
    bf16* xn2 = (bf16*)alloc((size_t)NTOK * DIMD * 2);
    bf16* qb  = (bf16*)alloc((size_t)NTOK * DIMD * 2);
    bf16* kb  = (bf16*)alloc((size_t)NTOK * DIMD * 2);
    bf16* vb  = (bf16*)alloc((size_t)NTOK * DIMD * 2);
    bf16* vTb = (bf16*)alloc((size_t)NTOK * DIMD * 2);
    bf16* ao  = (bf16*)alloc((size_t)NTOK * DIMD * 2);
    float* x1 = (float*)alloc((size_t)NTOK * DIMD * 4);
    bf16* hh  = (bf16*)alloc((size_t)NTOK * MLPH * 2);
    bf16* dtab = (bf16*)alloc((size_t)NBATCH * SEQ * SEQ * 2);  // 32 MiB (DP)
    if (off > ws_size) return;  // workspace too small; cannot run

    wtransall_k<<<1152, 256, 0, stream>>>(qkv_w, proj_w, mlp_w1, mlp_w2,
                                          WT1, WT2, WT3, WT4);

    dist_k<<<NBATCH * 32 * 4, 256, 0, stream>>>(pos, dtab);

    ln_k<<<NTOK / 4, 256, 0, stream>>>(x, ln1_g, ln1_b, xn);
    gemm128_k<0><<<dim3(1152 / 128, NTOK / 128), 256, 0, stream>>>(
        xn, WT1, qkv_b, qb, kb, vb, 384, 1152);
    vtrans_k<<<dim3(SEQ / 32, HD / 32, NBATCH * NHEADS), 256, 0, stream>>>(vb, vTb);
    attn_k<<<NBATCH * NHEADS * (SEQ / 64), 256, 0, stream>>>(qb, kb, vTb, dtab, ao);
    gemm_k<1><<<dim3(384 / 64, NTOK / 64), 256, 0, stream>>>(
        ao, WT2, proj_b, x, x1, 384, 384);
    ln_k<<<NTOK / 4, 256, 0, stream>>>(x1, ln2_g, ln2_b, xn2);
    gemm128_k<2><<<dim3(768 / 128, NTOK / 128), 256, 0, stream>>>(
        xn2, WT3, mlp_b1, hh, nullptr, nullptr, 384, 768);
    gemm_k<3><<<dim3(384 / 64, NTOK / 64), 256, 0, stream>>>(
        hh, WT4, mlp_b2, x1, (float*)d_out, 768, 384);
}

// Round 8
// 141.813 us; speedup vs baseline: 2.9039x; 1.0173x over previous
//
#include <hip/hip_runtime.h>
#include <hip/hip_bf16.h>
#include <math.h>

#define DIMD 384
#define NHEADS 6
#define HD 64
#define MLPH 768
#define SEQ 2048
#define NBATCH 4
#define NTOK (NBATCH*SEQ)   // 8192

typedef __hip_bfloat16 bf16;

typedef __attribute__((ext_vector_type(8))) short bf16x8;
typedef __attribute__((ext_vector_type(4))) float f32x4;

#define LOG2E 1.44269504088896340736f

static __device__ inline float fexp2(float x) { return __builtin_amdgcn_exp2f(x); }

static __device__ inline f32x4 mfma16(bf16x8 a, bf16x8 b, f32x4 c) {
    return __builtin_amdgcn_mfma_f32_16x16x32_bf16(a, b, c, 0, 0, 0);
}

// packed f32x2 -> bf16x2 (RNE), single instruction
static __device__ inline unsigned int cvtpk(float lo, float hi) {
    unsigned int r;
    asm("v_cvt_pk_bf16_f32 %0, %1, %2" : "=v"(r) : "v"(lo), "v"(hi));
    return r;
}
static __device__ inline float bflo(unsigned int u) { return __builtin_bit_cast(float, u << 16); }
static __device__ inline float bfhi(unsigned int u) { return __builtin_bit_cast(float, u & 0xffff0000u); }

// async global->LDS, 16B per lane. LDS dest must be wave-linear (base + lane*16).
static __device__ inline void gld16(const void* g, void* l) {
    __builtin_amdgcn_global_load_lds(
        (const __attribute__((address_space(1))) unsigned int*)g,
        (__attribute__((address_space(3))) unsigned int*)l, 16, 0, 0);
}

// ---------------------------------------------------------------- LayerNorm
__global__ __launch_bounds__(256) void ln_k(const float* __restrict__ x,
                                            const float* __restrict__ gm,
                                            const float* __restrict__ bt,
                                            bf16* __restrict__ out) {
    int row = blockIdx.x * 4 + (threadIdx.x >> 6);
    int l = threadIdx.x & 63;
    const float* xr = x + (size_t)row * DIMD;
    float v[6];
#pragma unroll
    for (int j = 0; j < 6; ++j) v[j] = xr[l + 64 * j];
    float s = 0.f, s2 = 0.f;
#pragma unroll
    for (int j = 0; j < 6; ++j) { s += v[j]; s2 += v[j] * v[j]; }
#pragma unroll
    for (int m = 1; m < 64; m <<= 1) { s += __shfl_xor(s, m); s2 += __shfl_xor(s2, m); }
    float mu = s * (1.f / DIMD);
    float var = s2 * (1.f / DIMD) - mu * mu;
    float rs = rsqrtf(var + 1e-5f);
    bf16* orow = out + (size_t)row * DIMD;
#pragma unroll
    for (int j = 0; j < 6; ++j) {
        int i = l + 64 * j;
        orow[i] = __float2bfloat16((v[j] - mu) * rs * gm[i] + bt[i]);
    }
}

// --------------------------------- prep: wtrans x4 + dist table + ln1, fused
// id <1152: weight transpose; <1664: dist table; else ln1 (2048 blocks)
__global__ __launch_bounds__(256) void prep_k(const float* __restrict__ w1,
                                              const float* __restrict__ w2,
                                              const float* __restrict__ w3,
                                              const float* __restrict__ w4,
                                              bf16* __restrict__ o1,
                                              bf16* __restrict__ o2,
                                              bf16* __restrict__ o3,
                                              bf16* __restrict__ o4,
                                              const float* __restrict__ pos,
                                              bf16* __restrict__ DP,
                                              const float* __restrict__ x,
                                              const float* __restrict__ g1,
                                              const float* __restrict__ b1,
                                              bf16* __restrict__ xn) {
    __shared__ float t[32][33];
    int id = blockIdx.x;
    if (id < 1152) {
        const float* W; bf16* O; int K, N;
        if (id < 432)      { W = w1; O = o1; K = 384; N = 1152; }
        else if (id < 576) { W = w2; O = o2; K = 384; N = 384;  id -= 432; }
        else if (id < 864) { W = w3; O = o3; K = 384; N = 768;  id -= 576; }
        else               { W = w4; O = o4; K = 768; N = 384;  id -= 864; }
        int nbx = N >> 5;
        int nb = (id % nbx) * 32, kb = (id / nbx) * 32;
        int tx = threadIdx.x & 31, ty = threadIdx.x >> 5;
#pragma unroll
        for (int i = 0; i < 4; ++i)
            t[ty + 8 * i][tx] = W[(size_t)(kb + ty + 8 * i) * N + nb + tx];
        __syncthreads();
#pragma unroll
        for (int i = 0; i < 4; ++i)
            O[(size_t)(nb + ty + 8 * i) * K + kb + tx] = __float2bfloat16(t[tx][ty + 8 * i]);
    } else if (id < 1664) {
        int blk = id - 1152;              // (b*32+qt)*4 + w
        int w = blk & 3, qt = (blk >> 2) & 31, b = blk >> 7;
        int l = threadIdx.x & 63, tt = threadIdx.x >> 6;
        int lq = l & 15, g = l >> 4;
        int q = qt * 64 + w * 16 + lq;
        const float* pq = pos + ((size_t)b * SEQ + q) * 3;
        float px = pq[0], py = pq[1], pz = pq[2];
        const float* posb = pos + (size_t)b * SEQ * 3;
        char* base = (char*)DP + (size_t)blk * 65536;
        for (int j = 0; j < 8; ++j) {
            int tt8 = tt * 8 + j;
#pragma unroll
            for (int m = 0; m < 2; ++m) {
                int k0 = tt8 * 64 + 32 * m + 4 * g;
                float a[24];
                const float* pk = posb + 3 * k0;
                *(f32x4*)&a[0]  = *(const f32x4*)pk;
                *(f32x4*)&a[4]  = *(const f32x4*)(pk + 4);
                *(f32x4*)&a[8]  = *(const f32x4*)(pk + 8);
                const float* pk2 = posb + 3 * (k0 + 16);
                *(f32x4*)&a[12] = *(const f32x4*)pk2;
                *(f32x4*)&a[16] = *(const f32x4*)(pk2 + 4);
                *(f32x4*)&a[20] = *(const f32x4*)(pk2 + 8);
                float o8[8];
#pragma unroll
                for (int r = 0; r < 8; ++r) {
                    float dx = px - a[3 * r], dy = py - a[3 * r + 1], dz = pz - a[3 * r + 2];
                    o8[r] = fexp2(-LOG2E * (dx * dx + dy * dy + dz * dz)) * LOG2E;
                }
                uint4 o;
                o.x = cvtpk(o8[0], o8[1]); o.y = cvtpk(o8[2], o8[3]);
                o.z = cvtpk(o8[4], o8[5]); o.w = cvtpk(o8[6], o8[7]);
                *(uint4*)(base + ((size_t)tt8 * 2 + m) * 1024 + l * 16) = o;
            }
        }
    } else {
        int row = (id - 1664) * 4 + (threadIdx.x >> 6);
        int l = threadIdx.x & 63;
        const float* xr = x + (size_t)row * DIMD;
        float v[6];
#pragma unroll
        for (int j = 0; j < 6; ++j) v[j] = xr[l + 64 * j];
        float s = 0.f, s2 = 0.f;
#pragma unroll
        for (int j = 0; j < 6; ++j) { s += v[j]; s2 += v[j] * v[j]; }
#pragma unroll
        for (int m = 1; m < 64; m <<= 1) { s += __shfl_xor(s, m); s2 += __shfl_xor(s2, m); }
        float mu = s * (1.f / DIMD);
        float var = s2 * (1.f / DIMD) - mu * mu;
        float rs = rsqrtf(var + 1e-5f);
        bf16* orow = xn + (size_t)row * DIMD;
#pragma unroll
        for (int j = 0; j < 6; ++j) {
            int i = l + 64 * j;
            orow[i] = __float2bfloat16((v[j] - mu) * rs * g1[i] + b1[i]);
        }
    }
}

// ------------------------------------------- GEMM 128x128 (m97 structure)
// EPI 0: qkv scatter (V written transposed+PV-permuted directly); 2: gelu.
template <int EPI>
__global__ __launch_bounds__(256) void gemm128_k(const bf16* __restrict__ A,
                                                 const bf16* __restrict__ WT,
                                                 const float* __restrict__ bias,
                                                 bf16* __restrict__ ob0,
                                                 bf16* __restrict__ ob1,
                                                 bf16* __restrict__ ob2,
                                                 int K, int Nw) {
    __shared__ __align__(16) char Als[2][8192];   // [128 m][32 k] bf16
    __shared__ __align__(16) char Bls[2][8192];   // [128 n][32 k] bf16
    int tid = threadIdx.x;
    int w = tid >> 6, l = tid & 63;
    int c = l & 15, g = l >> 4;
    int wr = w >> 1, wc = w & 1;
    int m0 = blockIdx.y * 128, n0 = blockIdx.x * 128;
    const char* Ag = (const char*)A + (size_t)m0 * K * 2;
    const char* Bg = (const char*)WT + (size_t)n0 * K * 2;
    int K2 = K * 2;

    f32x4 acc[4][4];
#pragma unroll
    for (int mi = 0; mi < 4; ++mi)
#pragma unroll
        for (int ni = 0; ni < 4; ++ni) acc[mi][ni] = (f32x4){0.f, 0.f, 0.f, 0.f};

    auto stage = [&](int t, int bi) {
#pragma unroll
        for (int p = 0; p < 2; ++p) {
            int chunk = p * 256 + tid;            // 512 x 16B per 8KB tile
            int r = chunk >> 2;                   // row 0..127 (64B rows)
            int cc = ((chunk & 3) ^ (r & 3)) << 4;
            gld16(Ag + (size_t)r * K2 + t * 64 + cc, &Als[bi][chunk * 16]);
            gld16(Bg + (size_t)r * K2 + t * 64 + cc, &Bls[bi][chunk * 16]);
        }
    };

    stage(0, 0);
    int kcn = K >> 5;
    for (int t = 0; t < kcn; ++t) {
        int bi = t & 1;
        __syncthreads();
        if (t + 1 < kcn) stage(t + 1, bi ^ 1);
        bf16x8 af[4], bfr[4];
#pragma unroll
        for (int mi = 0; mi < 4; ++mi) {
            int row = wr * 64 + mi * 16 + c;
            __builtin_memcpy(&af[mi], &Als[bi][row * 64 + ((g ^ (row & 3)) << 4)], 16);
        }
#pragma unroll
        for (int ni = 0; ni < 4; ++ni) {
            int row = wc * 64 + ni * 16 + c;
            __builtin_memcpy(&bfr[ni], &Bls[bi][row * 64 + ((g ^ (row & 3)) << 4)], 16);
        }
#pragma unroll
        for (int mi = 0; mi < 4; ++mi)
#pragma unroll
            for (int ni = 0; ni < 4; ++ni)
                acc[mi][ni] = mfma16(af[mi], bfr[ni], acc[mi][ni]);
    }

#pragma unroll
    for (int mi = 0; mi < 4; ++mi) {
#pragma unroll
        for (int ni = 0; ni < 4; ++ni) {
            int ntb = n0 + wc * 64 + ni * 16;
#pragma unroll
            for (int r = 0; r < 4; ++r) {
                int m = m0 + wr * 64 + mi * 16 + 4 * g + r;
                int n = ntb + c;
                float val = acc[mi][ni][r] + bias[n];
                if (EPI == 0) {
                    int which = ntb / DIMD;
                    int rem = ntb - which * DIMD;
                    int h = rem >> 6;
                    int d = (rem & 63) + c;
                    int b = m >> 11, s = m & (SEQ - 1);
                    if (which == 2) {
                        // V: write transposed + PV column permutation (invp)
                        int slot = (s & ~31) + 8 * ((m & 15) >> 2) + 4 * ((m >> 4) & 1) + (m & 3);
                        ob2[(((size_t)b * NHEADS + h) * HD + d) * SEQ + slot] = __float2bfloat16(val);
                    } else {
                        bf16* dp = which == 0 ? ob0 : ob1;
                        dp[(((size_t)b * NHEADS + h) * SEQ + s) * HD + d] = __float2bfloat16(val);
                    }
                } else {  // EPI 2: exact gelu -> bf16
                    float ge = 0.5f * val * (1.0f + erff(val * 0.70710678118654752f));
                    ob0[(size_t)m * Nw + n] = __float2bfloat16(ge);
                }
            }
        }
    }
}

// ---------------------------------------------------------------- GEMM 64x64
template <int EPI>
__global__ __launch_bounds__(256) void gemm_k(const bf16* __restrict__ A,
                                              const bf16* __restrict__ WT,
                                              const float* __restrict__ bias,
                                              const float* __restrict__ resid,
                                              float* __restrict__ outf,
                                              int K, int Nw) {
    __shared__ __align__(16) char Als[2][8192];   // [64 m][64 k] bf16
    __shared__ __align__(16) char Bls[2][8192];   // [64 n][64 k] bf16
    int tid = threadIdx.x;
    int w = tid >> 6, l = tid & 63;
    int c = l & 15, g = l >> 4;
    int m0 = blockIdx.y * 64, n0 = blockIdx.x * 64;
    const char* Ag = (const char*)A + (size_t)m0 * K * 2;
    const char* Bg = (const char*)WT + (size_t)n0 * K * 2;
    int K2 = K * 2;

    f32x4 acc[4];
#pragma unroll
    for (int nt = 0; nt < 4; ++nt) acc[nt] = (f32x4){0.f, 0.f, 0.f, 0.f};

    auto stage = [&](int t, int bi) {
#pragma unroll
        for (int p = 0; p < 2; ++p) {
            int chunk = p * 256 + tid;            // 512 x 16B per 8KB buffer
            int r = chunk >> 3;
            int cc = ((chunk & 7) ^ (r & 7)) << 4;
            gld16(Ag + (size_t)r * K2 + t * 128 + cc, &Als[bi][chunk * 16]);
            gld16(Bg + (size_t)r * K2 + t * 128 + cc, &Bls[bi][chunk * 16]);
        }
    };

    stage(0, 0);
    int kcn = K >> 6;
    int arow = (16 * w + c) * 128;
    int sw = c & 7;
    for (int t = 0; t < kcn; ++t) {
        int bi = t & 1;
        __syncthreads();
        if (t + 1 < kcn) stage(t + 1, bi ^ 1);
#pragma unroll
        for (int kk = 0; kk < 2; ++kk) {
            int ch = ((kk * 4 + g) ^ sw) << 4;
            bf16x8 af;
            __builtin_memcpy(&af, &Als[bi][arow + ch], 16);
#pragma unroll
            for (int nt = 0; nt < 4; ++nt) {
                bf16x8 bfr;
                __builtin_memcpy(&bfr, &Bls[bi][(nt * 16 + c) * 128 + ch], 16);
                acc[nt] = mfma16(af, bfr, acc[nt]);
            }
        }
    }

#pragma unroll
    for (int nt = 0; nt < 4; ++nt) {
        int ntb = n0 + nt * 16;
#pragma unroll
        for (int r = 0; r < 4; ++r) {
            int m = m0 + 16 * w + 4 * g + r;
            int n = ntb + c;
            float val = acc[nt][r] + bias[n];
            val += resid[(size_t)m * Nw + n];
            outf[(size_t)m * Nw + n] = val;
        }
    }
}

// ---------------------------------------------------------------- Attention
// 3-buffer counted-vmcnt pipeline: raw s_barrier + manual s_waitcnt vmcnt(4).
// stage(t) is always >=7 vmem instrs old at its wait -> vmcnt(4) drains it.
// Buffer (t+2)%3 == (t-1)%3 reuse is protected by the barrier at t.
// Row-sum via ones-MFMA: every lane ends holding its q-row's denominator.
__global__ __launch_bounds__(256) void attn_k(const bf16* __restrict__ q,
                                              const bf16* __restrict__ k,
                                              const bf16* __restrict__ vT,
                                              const bf16* __restrict__ DP,
                                              bf16* __restrict__ out) {
    __shared__ __align__(16) char Kls[3][8192];   // K  [64 k-rows][64 d]
    __shared__ __align__(16) char Vls[3][8192];   // V^T[64 d-rows][64 k] (permuted cols)

    int tid = threadIdx.x;
    int w = tid >> 6, l = tid & 63;
    int lq = l & 15, g = l >> 4;
    int qt = blockIdx.x & 31;
    int bh = blockIdx.x >> 5;
    int b = bh / NHEADS, h = bh % NHEADS;
    int qrow = qt * 64 + w * 16 + lq;

    const bf16* qp = q + ((size_t)bh * SEQ + qrow) * HD + 8 * g;
    bf16x8 qf0 = *(const bf16x8*)qp;
    bf16x8 qf1 = *(const bf16x8*)(qp + 32);

    const char* kgb = (const char*)(k + (size_t)bh * SEQ * HD);
    const char* vgb = (const char*)(vT + (size_t)bh * HD * SEQ);
    const char* dpb = (const char*)DP + ((size_t)((b * 32 + qt) * 4 + w)) * 65536 + l * 16;

    const float SC2 = 0.125f * LOG2E;
    f32x4 oacc[4];
#pragma unroll
    for (int dt = 0; dt < 4; ++dt) oacc[dt] = (f32x4){0.f, 0.f, 0.f, 0.f};
    f32x4 osum = (f32x4){0.f, 0.f, 0.f, 0.f};
    bf16x8 ones = {(short)0x3F80, (short)0x3F80, (short)0x3F80, (short)0x3F80,
                   (short)0x3F80, (short)0x3F80, (short)0x3F80, (short)0x3F80};

    auto stage = [&](int t, int bi) {
#pragma unroll
        for (int p = 0; p < 2; ++p) {
            int chunk = p * 256 + tid;
            int r = chunk >> 3, c = chunk & 7;
            int cc = (c ^ (r & 7)) << 4;
            gld16(kgb + (size_t)t * 8192 + r * 128 + cc, &Kls[bi][chunk * 16]);
            gld16(vgb + (size_t)r * 4096 + t * 128 + cc, &Vls[bi][chunk * 16]);
        }
    };

    stage(0, 0);
    uint4 cdp0 = *(const uint4*)(dpb);
    uint4 cdp1 = *(const uint4*)(dpb + 1024);
    stage(1, 1);

    int ib0 = 0, ib1 = 1, ib2 = 2;
    int swq = lq & 7;
    for (int t = 0; t < 32; ++t) {
        asm volatile("s_waitcnt vmcnt(4)" ::: "memory");
        __builtin_amdgcn_sched_barrier(0);
        __builtin_amdgcn_s_barrier();
        __builtin_amdgcn_sched_barrier(0);

        f32x4 st[4];
        __builtin_amdgcn_s_setprio(1);
#pragma unroll
        for (int s = 0; s < 4; ++s) {
            int ro = (16 * s + lq) * 128;
            bf16x8 klo, khi;
            __builtin_memcpy(&klo, &Kls[ib0][ro + ((g ^ swq) << 4)], 16);
            __builtin_memcpy(&khi, &Kls[ib0][ro + (((4 + g) ^ swq) << 4)], 16);
            f32x4 z = (f32x4){0.f, 0.f, 0.f, 0.f};
            st[s] = mfma16(klo, qf0, z);
            st[s] = mfma16(khi, qf1, st[s]);
        }
        __builtin_amdgcn_s_setprio(0);

#pragma unroll
        for (int m = 0; m < 2; ++m) {
            uint4 cd = m == 0 ? cdp0 : cdp1;
            f32x4 s0v = st[2 * m], s1v = st[2 * m + 1];
            float p[8];
            p[0] = fexp2(s0v[0] * SC2 + bflo(cd.x));
            p[1] = fexp2(s0v[1] * SC2 + bfhi(cd.x));
            p[2] = fexp2(s0v[2] * SC2 + bflo(cd.y));
            p[3] = fexp2(s0v[3] * SC2 + bfhi(cd.y));
            p[4] = fexp2(s1v[0] * SC2 + bflo(cd.z));
            p[5] = fexp2(s1v[1] * SC2 + bfhi(cd.z));
            p[6] = fexp2(s1v[2] * SC2 + bflo(cd.w));
            p[7] = fexp2(s1v[3] * SC2 + bfhi(cd.w));

            unsigned int pw[4];
            pw[0] = cvtpk(p[0], p[1]);
            pw[1] = cvtpk(p[2], p[3]);
            pw[2] = cvtpk(p[4], p[5]);
            pw[3] = cvtpk(p[6], p[7]);
            bf16x8 pf;
            __builtin_memcpy(&pf, pw, 16);

            __builtin_amdgcn_s_setprio(1);
            osum = mfma16(ones, pf, osum);
#pragma unroll
            for (int dt = 0; dt < 4; ++dt) {
                int rv = (16 * dt + lq) * 128;
                bf16x8 vf;
                __builtin_memcpy(&vf, &Vls[ib0][rv + (((4 * m + g) ^ swq) << 4)], 16);
                oacc[dt] = mfma16(vf, pf, oacc[dt]);
            }
            __builtin_amdgcn_s_setprio(0);
        }

        __builtin_amdgcn_sched_barrier(0);
        int tn1 = t + 1 < 32 ? t + 1 : 31;
        const char* dpn = dpb + (size_t)tn1 * 2048;
        uint4 ndp0 = *(const uint4*)(dpn);
        uint4 ndp1 = *(const uint4*)(dpn + 1024);
        __builtin_amdgcn_sched_barrier(0);
        int tn2 = t + 2 < 32 ? t + 2 : 31;
        stage(tn2, ib2);
        __builtin_amdgcn_sched_barrier(0);
        cdp0 = ndp0; cdp1 = ndp1;
        int tmp = ib0; ib0 = ib1; ib1 = ib2; ib2 = tmp;
    }

    float inv = 1.f / osum[0];      // every lane holds the full row denominator
    bf16* op = out + ((size_t)b * SEQ + qrow) * DIMD + h * HD + 4 * g;
#pragma unroll
    for (int dt = 0; dt < 4; ++dt) {
        unsigned int t2[2];
        t2[0] = cvtpk(oacc[dt][0] * inv, oacc[dt][1] * inv);
        t2[1] = cvtpk(oacc[dt][2] * inv, oacc[dt][3] * inv);
        __builtin_memcpy(op + dt * 16, t2, 8);
    }
}

// ---------------------------------------------------------------- launch
extern "C" void kernel_launch(void* const* d_in, const int* in_sizes, int n_in,
                              void* d_out, int out_size, void* d_ws, size_t ws_size,
                              hipStream_t stream) {
    const float* x      = (const float*)d_in[0];
    const float* pos    = (const float*)d_in[1];
    const float* qkv_w  = (const float*)d_in[2];
    const float* qkv_b  = (const float*)d_in[3];
    const float* proj_w = (const float*)d_in[4];
    const float* proj_b = (const float*)d_in[5];
    const float* mlp_w1 = (const float*)d_in[6];
    const float* mlp_b1 = (const float*)d_in[7];
    const float* mlp_w2 = (const float*)d_in[8];
    const float* mlp_b2 = (const float*)d_in[9];
    const float* ln1_g  = (const float*)d_in[10];
    const float* ln1_b  = (const float*)d_in[11];
    const float* ln2_g  = (const float*)d_in[12];
    const float* ln2_b  = (const float*)d_in[13];

    char* p = (char*)d_ws;
    size_t off = 0;
    auto alloc = [&](size_t bytes) {
        char* r = p + off;
        off = (off + bytes + 255) & ~(size_t)255;
        return r;
    };
    bf16* WT1 = (bf16*)alloc((size_t)1152 * 384 * 2);
    bf16* WT2 = (bf16*)alloc((size_t)384 * 384 * 2);
    bf16* WT3 = (bf16*)alloc((size_t)384 * 768 * 2);
    bf16* WT4 = (bf16*)alloc((size_t)768 * 384 * 2);
    bf16* xn  = (bf16*)alloc((size_t)NTOK * DIMD * 2);
    bf16* xn2 = (bf16*)alloc((size_t)NTOK * DIMD * 2);
    bf16* qb  = (bf16*)alloc((size_t)NTOK * DIMD * 2);
    bf16* kb  = (bf16*)alloc((size_t)NTOK * DIMD * 2);
    bf16* vTb = (bf16*)alloc((size_t)NTOK * DIMD * 2);
    bf16* ao  = (bf16*)alloc((size_t)NTOK * DIMD * 2);
    float* x1 = (float*)alloc((size_t)NTOK * DIMD * 4);
    bf16* hh  = (bf16*)alloc((size_t)NTOK * MLPH * 2);
    bf16* dtab = (bf16*)alloc((size_t)NBATCH * SEQ * SEQ * 2);  // 32 MiB (DP)
    if (off > ws_size) return;  // workspace too small; cannot run

    // prep: 4 weight transposes + dist table + ln1, one launch
    prep_k<<<1152 + 512 + 2048, 256, 0, stream>>>(
        qkv_w, proj_w, mlp_w1, mlp_w2, WT1, WT2, WT3, WT4,
        pos, dtab, x, ln1_g, ln1_b, xn);

    // qkv GEMM -> q, k, vT(direct transposed+permuted)
    gemm128_k<0><<<dim3(1152 / 128, NTOK / 128), 256, 0, stream>>>(
        xn, WT1, qkv_b, qb, kb, vTb, 384, 1152);
    attn_k<<<NBATCH * NHEADS * (SEQ / 64), 256, 0, stream>>>(qb, kb, vTb, dtab, ao);
    gemm_k<1><<<dim3(384 / 64, NTOK / 64), 256, 0, stream>>>(
        ao, WT2, proj_b, x, x1, 384, 384);
    ln_k<<<NTOK / 4, 256, 0, stream>>>(x1, ln2_g, ln2_b, xn2);
    gemm128_k<2><<<dim3(768 / 128, NTOK / 128), 256, 0, stream>>>(
        xn2, WT3, mlp_b1, hh, nullptr, nullptr, 384, 768);
    gemm_k<3><<<dim3(384 / 64, NTOK / 64), 256, 0, stream>>>(
        hh, WT4, mlp_b2, x1, (float*)d_out, 768, 384);
}